// Round 1
// baseline (5515.966 us; speedup 1.0000x reference)
//
#include <hip/hip_runtime.h>

// Problem constants
#define NB 32768
#define NT 16
#define NV 32001   // V+1
#define NE 32
#define NH 64
#define NTAGS 64

__device__ __forceinline__ float sigm_(float x) { return 1.0f / (1.0f + __expf(-x)); }
__device__ __forceinline__ float tanh_(float x) {
    x = fminf(fmaxf(x, -15.0f), 15.0f);
    float e = __expf(2.0f * x);
    return (e - 1.0f) / (e + 1.0f);
}

// ---------------- precompute: pack weights ----------------
// WhhP[k*64+j] = {Whh[j][k], Whh[j+64][k], Whh[j+128][k], Whh[j+192][k]}   (64x64 float4)
// WihPk[k*64+j] = {Wih[j][k], Wih[j+64][k], Wih[j+128][k], Wih[j+192][k]}  (32x64 float4)
// Wc2T[k*32+r]  = Wc[r][32+k]                                              (64x32 float)
// bsumP[j]      = {b[j], b[j+64], b[j+128], b[j+192]},  b = bih+bhh
__global__ void pre_pack(const float* __restrict__ Wih, const float* __restrict__ Whh,
                         const float* __restrict__ bih, const float* __restrict__ bhh,
                         const float* __restrict__ Wc,
                         float4* __restrict__ WhhP, float4* __restrict__ WihPk,
                         float* __restrict__ Wc2T, float4* __restrict__ bsumP) {
    int t = blockIdx.x * blockDim.x + threadIdx.x;  // 0..4095
    int k = t >> 6, j = t & 63;
    WhhP[k * 64 + j] = make_float4(Whh[j * 64 + k], Whh[(j + 64) * 64 + k],
                                   Whh[(j + 128) * 64 + k], Whh[(j + 192) * 64 + k]);
    if (k < 32)
        WihPk[k * 64 + j] = make_float4(Wih[j * 32 + k], Wih[(j + 64) * 32 + k],
                                        Wih[(j + 128) * 32 + k], Wih[(j + 192) * 32 + k]);
    if (j < 32) Wc2T[k * 32 + j] = Wc[j * 96 + 32 + k];
    if (k == 0)
        bsumP[j] = make_float4(bih[j] + bhh[j], bih[j + 64] + bhh[j + 64],
                               bih[j + 128] + bhh[j + 128], bih[j + 192] + bhh[j + 192]);
}

// ---------------- precompute: token tables ----------------
// Pp[v*64+j] = bsumP[j] + sum_k emb[v][k] * {Wih rows j,j+64,j+128,j+192}[k]
// Rc[v*32+r] = sum_k emb[v][k] * Wc[r][k]
__global__ __launch_bounds__(256) void pre_tok(const float* __restrict__ emb,
                                               const float4* __restrict__ WihPk,
                                               const float* __restrict__ Wc,
                                               const float4* __restrict__ bsumP,
                                               float4* __restrict__ Pp, float* __restrict__ Rc) {
    int wave = threadIdx.x >> 6, j = threadIdx.x & 63;
    int v = blockIdx.x * 4 + wave;
    if (v >= NV) return;
    const float* ev = emb + v * NE;
    float4 a = bsumP[j];
#pragma unroll
    for (int k = 0; k < 32; ++k) {
        float e = ev[k];
        float4 w = WihPk[k * 64 + j];
        a.x = fmaf(e, w.x, a.x); a.y = fmaf(e, w.y, a.y);
        a.z = fmaf(e, w.z, a.z); a.w = fmaf(e, w.w, a.w);
    }
    Pp[v * 64 + j] = a;
    if (j < 32) {
        float r = 0.f;
#pragma unroll
        for (int k = 0; k < 32; ++k) r = fmaf(ev[k], Wc[j * 96 + k], r);
        Rc[v * 32 + j] = r;
    }
}

// ---------------- main: one wave per batch row ----------------
template <bool TABLES>
__global__ __launch_bounds__(512) void tagger_main(
    const int* __restrict__ x, const int* __restrict__ s, const float* __restrict__ emb,
    const float* __restrict__ Wih, const float* __restrict__ Whh,
    const float* __restrict__ bih, const float* __restrict__ bhh,
    const float* __restrict__ h0, const float* __restrict__ c0,
    const float* __restrict__ Wc, const float* __restrict__ bc,
    const float* __restrict__ Wt, const float* __restrict__ bt,
    const float4* __restrict__ Pp, const float* __restrict__ Rc,
    const float4* __restrict__ WhhPg, const float4* __restrict__ WihPk,
    const float* __restrict__ Wc2T, const float4* __restrict__ bsumP,
    float* __restrict__ out) {
    __shared__ float4 WhhP[4096];        // 64 KB: [k][j] -> rows {j, j+64, j+128, j+192}
    __shared__ float combBuf[8][128];    // per-wave comb_0..3 (32 floats each)

    if constexpr (TABLES) {
        for (int i = threadIdx.x; i < 4096; i += 512) WhhP[i] = WhhPg[i];
    } else {
        for (int i = threadIdx.x; i < 4096; i += 512) {
            int k = i & 63, jj = i >> 6;  // coalesced global read, scattered LDS write (once)
            WhhP[k * 64 + jj] = make_float4(Whh[jj * 64 + k], Whh[(jj + 64) * 64 + k],
                                            Whh[(jj + 128) * 64 + k], Whh[(jj + 192) * 64 + k]);
        }
    }
    __syncthreads();

    const int wave = threadIdx.x >> 6;
    const int j = threadIdx.x & 63;
    const int jm = j & 31;
    const int b = blockIdx.x * 8 + wave;
    const int sv = s[b];
    const int* xb = x + b * NT;
    const float bcj = bc[jm];

    auto rc_val = [&](int tok) -> float {
        if constexpr (TABLES) {
            return Rc[tok * 32 + jm];
        } else {
            float r = 0.f;
#pragma unroll
            for (int k = 0; k < 32; ++k) r = fmaf(emb[tok * NE + k], Wc[jm * 96 + k], r);
            return r;
        }
    };

    float comb4;
    if (sv >= 4) {
        // ---- heavy path: full 5-node tree-LSTM (wave-uniform branch) ----
        const float h0j = h0[j], c0j = c0[j];
        float4 bsj;
        if constexpr (TABLES) {
            bsj = bsumP[j];
        } else {
            bsj = make_float4(bih[j] + bhh[j], bih[j + 64] + bhh[j + 64],
                              bih[j + 128] + bhh[j + 128], bih[j + 192] + bhh[j + 192]);
        }
#pragma unroll 1
        for (int node = 0; node < 4; ++node) {
            float h = h0j, c = c0j;
#pragma unroll 1
            for (int t = 0; t < 4; ++t) {
                int tok = xb[node * 4 + t];
                float4 p;  // input projection + bias (load early, consume late)
                if constexpr (TABLES) {
                    p = Pp[tok * 64 + j];
                } else {
                    p = bsj;
#pragma unroll
                    for (int k = 0; k < 32; ++k) {
                        float e = emb[tok * NE + k];
                        p.x = fmaf(e, Wih[j * 32 + k], p.x);
                        p.y = fmaf(e, Wih[(j + 64) * 32 + k], p.y);
                        p.z = fmaf(e, Wih[(j + 128) * 32 + k], p.z);
                        p.w = fmaf(e, Wih[(j + 192) * 32 + k], p.w);
                    }
                }
                float4 a = make_float4(0.f, 0.f, 0.f, 0.f);
#pragma unroll
                for (int k = 0; k < 64; ++k) {
                    float hk = __shfl(h, k);  // const lane -> v_readlane (SALU broadcast)
                    float4 w = WhhP[k * 64 + j];
                    a.x = fmaf(hk, w.x, a.x); a.y = fmaf(hk, w.y, a.y);
                    a.z = fmaf(hk, w.z, a.z); a.w = fmaf(hk, w.w, a.w);
                }
                a.x += p.x; a.y += p.y; a.z += p.z; a.w += p.w;
                float ig = sigm_(a.x), fg = sigm_(a.y), gg = tanh_(a.z), og = sigm_(a.w);
                c = fmaf(fg, c, ig * gg);
                h = og * tanh_(c);
            }
            float last = fmaxf(h, 0.f);  // s==4 => mask[3]==1
            float acc = rc_val(xb[node * 4]) + bcj;
#pragma unroll
            for (int k = 0; k < 64; ++k) {
                float lk = __shfl(last, k);
                float w;
                if constexpr (TABLES) w = Wc2T[k * 32 + jm];
                else                  w = Wc[jm * 96 + 32 + k];
                acc = fmaf(lk, w, acc);
            }
            if (j < 32) combBuf[wave][node * 32 + j] = fmaxf(acc, 0.f);
        }
        // same-wave LDS write->read; DS pipe is in-order, stop compiler reordering:
        asm volatile("s_waitcnt lgkmcnt(0)" ::: "memory");

        // node 4: children are comb_0..3
        float h = h0j, c = c0j;
#pragma unroll 1
        for (int t = 0; t < 4; ++t) {
            float4 a = make_float4(0.f, 0.f, 0.f, 0.f);
#pragma unroll
            for (int k = 0; k < 32; ++k) {
                float ck = combBuf[wave][t * 32 + k];  // broadcast LDS read
                if constexpr (TABLES) {
                    float4 w = WihPk[k * 64 + j];
                    a.x = fmaf(ck, w.x, a.x); a.y = fmaf(ck, w.y, a.y);
                    a.z = fmaf(ck, w.z, a.z); a.w = fmaf(ck, w.w, a.w);
                } else {
                    a.x = fmaf(ck, Wih[j * 32 + k], a.x);
                    a.y = fmaf(ck, Wih[(j + 64) * 32 + k], a.y);
                    a.z = fmaf(ck, Wih[(j + 128) * 32 + k], a.z);
                    a.w = fmaf(ck, Wih[(j + 192) * 32 + k], a.w);
                }
            }
#pragma unroll
            for (int k = 0; k < 64; ++k) {
                float hk = __shfl(h, k);
                float4 w = WhhP[k * 64 + j];
                a.x = fmaf(hk, w.x, a.x); a.y = fmaf(hk, w.y, a.y);
                a.z = fmaf(hk, w.z, a.z); a.w = fmaf(hk, w.w, a.w);
            }
            a.x += bsj.x; a.y += bsj.y; a.z += bsj.z; a.w += bsj.w;
            float ig = sigm_(a.x), fg = sigm_(a.y), gg = tanh_(a.z), og = sigm_(a.w);
            c = fmaf(fg, c, ig * gg);
            h = og * tanh_(c);
        }
        float last = fmaxf(h, 0.f);
        float acc = rc_val(xb[0]) + bcj;
#pragma unroll
        for (int k = 0; k < 64; ++k) {
            float lk = __shfl(last, k);
            float w;
            if constexpr (TABLES) w = Wc2T[k * 32 + jm];
            else                  w = Wc[jm * 96 + 32 + k];
            acc = fmaf(lk, w, acc);
        }
        comb4 = fmaxf(acc, 0.f);
    } else {
        // ---- light path: last == 0 everywhere -> comb4 = relu(Rc[x0] + bc) ----
        comb4 = fmaxf(rc_val(xb[0]) + bcj, 0.f);
    }

    // logits + log_softmax across the wave (lane j = tag j)
    float logit = bt[j];
    const float* wtr = Wt + j * 32;
#pragma unroll
    for (int k = 0; k < 32; ++k) {
        float ck = __shfl(comb4, k);  // comb4[k] lives on lane k (k<32)
        logit = fmaf(ck, wtr[k], logit);
    }
    float mx = logit;
#pragma unroll
    for (int off = 32; off; off >>= 1) mx = fmaxf(mx, __shfl_xor(mx, off));
    float ex = __expf(logit - mx);
    float sum = ex;
#pragma unroll
    for (int off = 32; off; off >>= 1) sum += __shfl_xor(sum, off);
    out[b * 64 + j] = logit - mx - __logf(sum);
}

extern "C" void kernel_launch(void* const* d_in, const int* in_sizes, int n_in,
                              void* d_out, int out_size, void* d_ws, size_t ws_size,
                              hipStream_t stream) {
    const int* x = (const int*)d_in[0];
    const int* s = (const int*)d_in[1];
    const float* emb = (const float*)d_in[2];
    const float* Wih = (const float*)d_in[3];
    const float* Whh = (const float*)d_in[4];
    const float* bih = (const float*)d_in[5];
    const float* bhh = (const float*)d_in[6];
    const float* h0 = (const float*)d_in[7];
    const float* c0 = (const float*)d_in[8];
    const float* Wc = (const float*)d_in[9];
    const float* bc = (const float*)d_in[10];
    const float* Wt = (const float*)d_in[11];
    const float* bt = (const float*)d_in[12];
    float* out = (float*)d_out;

    // ws layout
    size_t offPp = 0;                                          // 32001*64*16 B
    size_t offRc = offPp + (size_t)NV * 64 * sizeof(float4);   // 32001*32*4 B
    size_t offWhhP = offRc + (size_t)NV * 32 * sizeof(float);  // 64 KB
    size_t offWihPk = offWhhP + 4096 * sizeof(float4);         // 32 KB
    size_t offWc2T = offWihPk + 2048 * sizeof(float4);         // 8 KB
    size_t offBsum = offWc2T + 2048 * sizeof(float);           // 1 KB
    size_t need = offBsum + 64 * sizeof(float4);               // ~37 MB total

    char* ws = (char*)d_ws;
    if (ws_size >= need) {
        float4* Pp = (float4*)(ws + offPp);
        float* Rc = (float*)(ws + offRc);
        float4* WhhP = (float4*)(ws + offWhhP);
        float4* WihPk = (float4*)(ws + offWihPk);
        float* Wc2T = (float*)(ws + offWc2T);
        float4* bsumP = (float4*)(ws + offBsum);
        pre_pack<<<dim3(16), dim3(256), 0, stream>>>(Wih, Whh, bih, bhh, Wc, WhhP, WihPk, Wc2T, bsumP);
        pre_tok<<<dim3(8001), dim3(256), 0, stream>>>(emb, WihPk, Wc, bsumP, Pp, Rc);
        tagger_main<true><<<dim3(4096), dim3(512), 0, stream>>>(
            x, s, emb, Wih, Whh, bih, bhh, h0, c0, Wc, bc, Wt, bt,
            Pp, Rc, WhhP, WihPk, Wc2T, bsumP, out);
    } else {
        tagger_main<false><<<dim3(4096), dim3(512), 0, stream>>>(
            x, s, emb, Wih, Whh, bih, bhh, h0, c0, Wc, bc, Wt, bt,
            nullptr, nullptr, nullptr, nullptr, nullptr, nullptr, out);
    }
}

// Round 2
// 494.101 us; speedup vs baseline: 11.1636x; 11.1636x over previous
//
#include <hip/hip_runtime.h>

// Problem constants
#define NB 32768
#define NT 16
#define NV 32001   // V+1
#define NE 32
#define NH 64
#define NTAGS 64

__device__ __forceinline__ float sigm_(float x) { return 1.0f / (1.0f + __expf(-x)); }
__device__ __forceinline__ float tanh_(float x) {
    x = fminf(fmaxf(x, -15.0f), 15.0f);
    float e = __expf(2.0f * x);
    return (e - 1.0f) / (e + 1.0f);
}

// ---------------- precompute: pack weights ----------------
// WhhP[k*64+j]  = {Whh[j][k], Whh[j+64][k], Whh[j+128][k], Whh[j+192][k]}   (64x64 float4)
// WihPk[k*64+j] = {Wih[j][k], Wih[j+64][k], Wih[j+128][k], Wih[j+192][k]}   (32x64 float4)
// Wc2P[k4*32+r] = {Wc[r][32+4k4+0..3]}                                       (16x32 float4)
// bsumP[j]      = {b[j], b[j+64], b[j+128], b[j+192]},  b = bih+bhh
__global__ void pre_pack(const float* __restrict__ Wih, const float* __restrict__ Whh,
                         const float* __restrict__ bih, const float* __restrict__ bhh,
                         const float* __restrict__ Wc,
                         float4* __restrict__ WhhP, float4* __restrict__ WihPk,
                         float4* __restrict__ Wc2P, float4* __restrict__ bsumP) {
    int t = blockIdx.x * blockDim.x + threadIdx.x;  // 0..4095
    int k = t >> 6, j = t & 63;
    WhhP[k * 64 + j] = make_float4(Whh[j * 64 + k], Whh[(j + 64) * 64 + k],
                                   Whh[(j + 128) * 64 + k], Whh[(j + 192) * 64 + k]);
    if (k < 32)
        WihPk[k * 64 + j] = make_float4(Wih[j * 32 + k], Wih[(j + 64) * 32 + k],
                                        Wih[(j + 128) * 32 + k], Wih[(j + 192) * 32 + k]);
    if (t < 512) {
        int k4 = t >> 5, r = t & 31;
        const float* p = Wc + r * 96 + 32 + 4 * k4;
        Wc2P[k4 * 32 + r] = make_float4(p[0], p[1], p[2], p[3]);
    }
    if (k == 0)
        bsumP[j] = make_float4(bih[j] + bhh[j], bih[j + 64] + bhh[j + 64],
                               bih[j + 128] + bhh[j + 128], bih[j + 192] + bhh[j + 192]);
}

// ---------------- precompute: token tables ----------------
// Pp[v*64+j] = bsumP[j] + sum_k emb[v][k] * {Wih rows j,j+64,j+128,j+192}[k]
// Rc[v*32+r] = sum_k emb[v][k] * Wc[r][k]
__global__ __launch_bounds__(256) void pre_tok(const float* __restrict__ emb,
                                               const float4* __restrict__ WihPk,
                                               const float* __restrict__ Wc,
                                               const float4* __restrict__ bsumP,
                                               float4* __restrict__ Pp, float* __restrict__ Rc) {
    int wave = threadIdx.x >> 6, j = threadIdx.x & 63;
    int v = blockIdx.x * 4 + wave;
    if (v >= NV) return;
    const float* ev = emb + v * NE;
    float4 a = bsumP[j];
#pragma unroll
    for (int k = 0; k < 32; ++k) {
        float e = ev[k];
        float4 w = WihPk[k * 64 + j];
        a.x = fmaf(e, w.x, a.x); a.y = fmaf(e, w.y, a.y);
        a.z = fmaf(e, w.z, a.z); a.w = fmaf(e, w.w, a.w);
    }
    Pp[v * 64 + j] = a;
    if (j < 32) {
        float r = 0.f;
#pragma unroll
        for (int k = 0; k < 32; ++k) r = fmaf(ev[k], Wc[j * 96 + k], r);
        Rc[v * 32 + j] = r;
    }
}

// ---------------- precompute: per-vocab light-path output table ----------------
// Light rows (s<4): last==0 at every node => out depends only on x[b,0].
// Lv[v][0..63] = log_softmax(relu(Rc[v]+bc) @ Wt^T + bt)
__global__ __launch_bounds__(256) void pre_light(const float* __restrict__ Rc,
                                                 const float* __restrict__ bc,
                                                 const float* __restrict__ Wt,
                                                 const float* __restrict__ bt,
                                                 float* __restrict__ Lv) {
    int wave = threadIdx.x >> 6, j = threadIdx.x & 63, jm = j & 31;
    int v = blockIdx.x * 4 + wave;
    if (v >= NV) return;
    float combv = fmaxf(Rc[v * 32 + jm] + bc[jm], 0.f);  // lane jm (and jm+32) hold comb[jm]
    float logit = bt[j];
    const float4* WtR = (const float4*)(Wt + j * 32);
#pragma unroll
    for (int k4 = 0; k4 < 8; ++k4) {
        float4 w = WtR[k4];
        logit = fmaf(__shfl(combv, 4 * k4 + 0), w.x, logit);
        logit = fmaf(__shfl(combv, 4 * k4 + 1), w.y, logit);
        logit = fmaf(__shfl(combv, 4 * k4 + 2), w.z, logit);
        logit = fmaf(__shfl(combv, 4 * k4 + 3), w.w, logit);
    }
    float mx = logit;
#pragma unroll
    for (int off = 32; off; off >>= 1) mx = fmaxf(mx, __shfl_xor(mx, off));
    float ex = __expf(logit - mx);
    float sum = ex;
#pragma unroll
    for (int off = 32; off; off >>= 1) sum += __shfl_xor(sum, off);
    Lv[v * 64 + j] = logit - mx - __logf(sum);
}

// ---------------- classify: light rows -> gather Lv; heavy rows -> compact list ----------------
__global__ __launch_bounds__(256) void classify(const int* __restrict__ x, const int* __restrict__ s,
                                                const float* __restrict__ Lv,
                                                int* __restrict__ cnt, int* __restrict__ list,
                                                float* __restrict__ out) {
    int gw = (blockIdx.x * 256 + threadIdx.x) >> 6;  // row
    int j = threadIdx.x & 63;
    if (gw >= NB) return;
    if (s[gw] >= 4) {
        if (j == 0) {
            int p = atomicAdd(cnt, 1);
            list[p] = gw;
        }
    } else {
        int tok = x[gw * NT];
        out[gw * 64 + j] = Lv[tok * 64 + j];
    }
}

// ---------------- heavy: one wave per s==4 row ----------------
__global__ __launch_bounds__(512) void heavy_kernel(
    const int* __restrict__ x,
    const float* __restrict__ h0, const float* __restrict__ c0,
    const float* __restrict__ bc, const float* __restrict__ Wt, const float* __restrict__ bt,
    const float4* __restrict__ Pp, const float* __restrict__ Rc,
    const float4* __restrict__ WhhPg, const float4* __restrict__ WihPk,
    const float4* __restrict__ Wc2P, const float4* __restrict__ bsumP,
    const int* __restrict__ cnt, const int* __restrict__ list,
    float* __restrict__ out) {
    __shared__ float4 WhhP[4096];                     // 64 KB
    __shared__ __align__(16) float hBuf[8][64];       // per-wave h / last / comb4 staging
    __shared__ __align__(16) float combBuf[8][128];   // per-wave comb_0..3

    const int nheavy = *cnt;
    if (blockIdx.x * 8 >= nheavy) return;             // fully-dead block: exit before staging

    for (int i = threadIdx.x; i < 4096; i += 512) WhhP[i] = WhhPg[i];
    __syncthreads();

    const int wave = threadIdx.x >> 6;
    const int j = threadIdx.x & 63;
    const int jm = j & 31;
    const int idx = blockIdx.x * 8 + wave;
    if (idx >= nheavy) return;                        // no barriers after this point
    const int b = list[idx];
    const int* xb = x + b * NT;
    const float h0j = h0[j], c0j = c0[j];
    const float bcj = bc[jm];
    const float4 bsj = bsumP[j];
    const float4* hb4 = (const float4*)hBuf[wave];
    const float4* cb4 = (const float4*)combBuf[wave];
    const float4* wcol = &WhhP[j];                    // stride 64 float4 (1024 B) per k

    // recurrent matvec: a += Whh(.)h using LDS-broadcast h + lane-distributed weights
#define K_LOOP(AV)                                                              \
    _Pragma("unroll")                                                           \
    for (int k4 = 0; k4 < 16; ++k4) {                                           \
        float4 hv = hb4[k4];                                                    \
        float4 w0 = wcol[(4 * k4 + 0) * 64];                                    \
        float4 w1 = wcol[(4 * k4 + 1) * 64];                                    \
        float4 w2 = wcol[(4 * k4 + 2) * 64];                                    \
        float4 w3 = wcol[(4 * k4 + 3) * 64];                                    \
        AV.x = fmaf(hv.x, w0.x, AV.x); AV.y = fmaf(hv.x, w0.y, AV.y);           \
        AV.z = fmaf(hv.x, w0.z, AV.z); AV.w = fmaf(hv.x, w0.w, AV.w);           \
        AV.x = fmaf(hv.y, w1.x, AV.x); AV.y = fmaf(hv.y, w1.y, AV.y);           \
        AV.z = fmaf(hv.y, w1.z, AV.z); AV.w = fmaf(hv.y, w1.w, AV.w);           \
        AV.x = fmaf(hv.z, w2.x, AV.x); AV.y = fmaf(hv.z, w2.y, AV.y);           \
        AV.z = fmaf(hv.z, w2.z, AV.z); AV.w = fmaf(hv.z, w2.w, AV.w);           \
        AV.x = fmaf(hv.w, w3.x, AV.x); AV.y = fmaf(hv.w, w3.y, AV.y);           \
        AV.z = fmaf(hv.w, w3.z, AV.z); AV.w = fmaf(hv.w, w3.w, AV.w);           \
    }

#pragma unroll 1
    for (int node = 0; node < 4; ++node) {
        float h = h0j, c = c0j;
#pragma unroll 1
        for (int t = 0; t < 4; ++t) {
            int tok = xb[node * 4 + t];
            float4 a = Pp[tok * 64 + j];              // proj+bias (global gather, issued early)
            hBuf[wave][j] = h;
            asm volatile("s_waitcnt lgkmcnt(0)" ::: "memory");
            K_LOOP(a)
            float ig = sigm_(a.x), fg = sigm_(a.y), gg = tanh_(a.z), og = sigm_(a.w);
            c = fmaf(fg, c, ig * gg);
            h = og * tanh_(c);
        }
        float last = fmaxf(h, 0.f);                   // s==4 => step-3 mask == 1
        hBuf[wave][j] = last;
        asm volatile("s_waitcnt lgkmcnt(0)" ::: "memory");
        float acc = Rc[xb[node * 4] * 32 + jm] + bcj;
#pragma unroll
        for (int k4 = 0; k4 < 16; ++k4) {
            float4 lv = hb4[k4];
            float4 w = Wc2P[k4 * 32 + jm];            // global, L2-hot (8 KB)
            acc = fmaf(lv.x, w.x, acc); acc = fmaf(lv.y, w.y, acc);
            acc = fmaf(lv.z, w.z, acc); acc = fmaf(lv.w, w.w, acc);
        }
        if (j < 32) combBuf[wave][node * 32 + j] = fmaxf(acc, 0.f);
        asm volatile("s_waitcnt lgkmcnt(0)" ::: "memory");
    }

    // node 4: children are comb_0..3
    float h = h0j, c = c0j;
#pragma unroll 1
    for (int t = 0; t < 4; ++t) {
        float4 a = bsj;
#pragma unroll
        for (int k4 = 0; k4 < 8; ++k4) {              // input proj from comb_t (32 values)
            float4 cv = cb4[t * 8 + k4];
            float4 w0 = WihPk[(4 * k4 + 0) * 64 + j]; // global, L2-hot (32 KB)
            float4 w1 = WihPk[(4 * k4 + 1) * 64 + j];
            float4 w2 = WihPk[(4 * k4 + 2) * 64 + j];
            float4 w3 = WihPk[(4 * k4 + 3) * 64 + j];
            a.x = fmaf(cv.x, w0.x, a.x); a.y = fmaf(cv.x, w0.y, a.y);
            a.z = fmaf(cv.x, w0.z, a.z); a.w = fmaf(cv.x, w0.w, a.w);
            a.x = fmaf(cv.y, w1.x, a.x); a.y = fmaf(cv.y, w1.y, a.y);
            a.z = fmaf(cv.y, w1.z, a.z); a.w = fmaf(cv.y, w1.w, a.w);
            a.x = fmaf(cv.z, w2.x, a.x); a.y = fmaf(cv.z, w2.y, a.y);
            a.z = fmaf(cv.z, w2.z, a.z); a.w = fmaf(cv.z, w2.w, a.w);
            a.x = fmaf(cv.w, w3.x, a.x); a.y = fmaf(cv.w, w3.y, a.y);
            a.z = fmaf(cv.w, w3.z, a.z); a.w = fmaf(cv.w, w3.w, a.w);
        }
        hBuf[wave][j] = h;
        asm volatile("s_waitcnt lgkmcnt(0)" ::: "memory");
        K_LOOP(a)
        float ig = sigm_(a.x), fg = sigm_(a.y), gg = tanh_(a.z), og = sigm_(a.w);
        c = fmaf(fg, c, ig * gg);
        h = og * tanh_(c);
    }
    float last = fmaxf(h, 0.f);
    hBuf[wave][j] = last;
    asm volatile("s_waitcnt lgkmcnt(0)" ::: "memory");
    float acc = Rc[xb[0] * 32 + jm] + bcj;
#pragma unroll
    for (int k4 = 0; k4 < 16; ++k4) {
        float4 lv = hb4[k4];
        float4 w = Wc2P[k4 * 32 + jm];
        acc = fmaf(lv.x, w.x, acc); acc = fmaf(lv.y, w.y, acc);
        acc = fmaf(lv.z, w.z, acc); acc = fmaf(lv.w, w.w, acc);
    }
    float comb4 = fmaxf(acc, 0.f);

    // logits + log_softmax (comb4[0..31] via LDS broadcast)
    hBuf[wave][j] = comb4;
    asm volatile("s_waitcnt lgkmcnt(0)" ::: "memory");
    float logit = bt[j];
    const float4* WtR = (const float4*)(Wt + j * 32);
#pragma unroll
    for (int k4 = 0; k4 < 8; ++k4) {
        float4 cv = hb4[k4];
        float4 w = WtR[k4];
        logit = fmaf(cv.x, w.x, logit); logit = fmaf(cv.y, w.y, logit);
        logit = fmaf(cv.z, w.z, logit); logit = fmaf(cv.w, w.w, logit);
    }
    float mx = logit;
#pragma unroll
    for (int off = 32; off; off >>= 1) mx = fmaxf(mx, __shfl_xor(mx, off));
    float ex = __expf(logit - mx);
    float sum = ex;
#pragma unroll
    for (int off = 32; off; off >>= 1) sum += __shfl_xor(sum, off);
    out[b * 64 + j] = logit - mx - __logf(sum);
#undef K_LOOP
}

// ---------------- fallback (small ws): round-1 monolithic kernel, no tables ----------------
__global__ __launch_bounds__(512) void tagger_fallback(
    const int* __restrict__ x, const int* __restrict__ s, const float* __restrict__ emb,
    const float* __restrict__ Wih, const float* __restrict__ Whh,
    const float* __restrict__ bih, const float* __restrict__ bhh,
    const float* __restrict__ h0, const float* __restrict__ c0,
    const float* __restrict__ Wc, const float* __restrict__ bc,
    const float* __restrict__ Wt, const float* __restrict__ bt,
    float* __restrict__ out) {
    __shared__ float4 WhhP[4096];
    __shared__ float combBuf[8][128];
    for (int i = threadIdx.x; i < 4096; i += 512) {
        int k = i & 63, jj = i >> 6;
        WhhP[k * 64 + jj] = make_float4(Whh[jj * 64 + k], Whh[(jj + 64) * 64 + k],
                                        Whh[(jj + 128) * 64 + k], Whh[(jj + 192) * 64 + k]);
    }
    __syncthreads();
    const int wave = threadIdx.x >> 6, j = threadIdx.x & 63, jm = j & 31;
    const int b = blockIdx.x * 8 + wave;
    const int sv = s[b];
    const int* xb = x + b * NT;
    const float bcj = bc[jm];
    auto rc_val = [&](int tok) -> float {
        float r = 0.f;
#pragma unroll
        for (int k = 0; k < 32; ++k) r = fmaf(emb[tok * NE + k], Wc[jm * 96 + k], r);
        return r;
    };
    float comb4;
    if (sv >= 4) {
        const float h0j = h0[j], c0j = c0[j];
        float4 bsj = make_float4(bih[j] + bhh[j], bih[j + 64] + bhh[j + 64],
                                 bih[j + 128] + bhh[j + 128], bih[j + 192] + bhh[j + 192]);
#pragma unroll 1
        for (int node = 0; node < 4; ++node) {
            float h = h0j, c = c0j;
#pragma unroll 1
            for (int t = 0; t < 4; ++t) {
                int tok = xb[node * 4 + t];
                float4 p = bsj;
#pragma unroll
                for (int k = 0; k < 32; ++k) {
                    float e = emb[tok * NE + k];
                    p.x = fmaf(e, Wih[j * 32 + k], p.x);
                    p.y = fmaf(e, Wih[(j + 64) * 32 + k], p.y);
                    p.z = fmaf(e, Wih[(j + 128) * 32 + k], p.z);
                    p.w = fmaf(e, Wih[(j + 192) * 32 + k], p.w);
                }
                float4 a = make_float4(0.f, 0.f, 0.f, 0.f);
#pragma unroll
                for (int k = 0; k < 64; ++k) {
                    float hk = __shfl(h, k);
                    float4 w = WhhP[k * 64 + j];
                    a.x = fmaf(hk, w.x, a.x); a.y = fmaf(hk, w.y, a.y);
                    a.z = fmaf(hk, w.z, a.z); a.w = fmaf(hk, w.w, a.w);
                }
                a.x += p.x; a.y += p.y; a.z += p.z; a.w += p.w;
                float ig = sigm_(a.x), fg = sigm_(a.y), gg = tanh_(a.z), og = sigm_(a.w);
                c = fmaf(fg, c, ig * gg);
                h = og * tanh_(c);
            }
            float last = fmaxf(h, 0.f);
            float acc = rc_val(xb[node * 4]) + bcj;
#pragma unroll
            for (int k = 0; k < 64; ++k)
                acc = fmaf(__shfl(last, k), Wc[jm * 96 + 32 + k], acc);
            if (j < 32) combBuf[wave][node * 32 + j] = fmaxf(acc, 0.f);
        }
        asm volatile("s_waitcnt lgkmcnt(0)" ::: "memory");
        float h = h0j, c = c0j;
#pragma unroll 1
        for (int t = 0; t < 4; ++t) {
            float4 a = make_float4(0.f, 0.f, 0.f, 0.f);
#pragma unroll
            for (int k = 0; k < 32; ++k) {
                float ck = combBuf[wave][t * 32 + k];
                a.x = fmaf(ck, Wih[j * 32 + k], a.x);
                a.y = fmaf(ck, Wih[(j + 64) * 32 + k], a.y);
                a.z = fmaf(ck, Wih[(j + 128) * 32 + k], a.z);
                a.w = fmaf(ck, Wih[(j + 192) * 32 + k], a.w);
            }
#pragma unroll
            for (int k = 0; k < 64; ++k) {
                float hk = __shfl(h, k);
                float4 w = WhhP[k * 64 + j];
                a.x = fmaf(hk, w.x, a.x); a.y = fmaf(hk, w.y, a.y);
                a.z = fmaf(hk, w.z, a.z); a.w = fmaf(hk, w.w, a.w);
            }
            a.x += bih[j] + bhh[j]; a.y += bih[j + 64] + bhh[j + 64];
            a.z += bih[j + 128] + bhh[j + 128]; a.w += bih[j + 192] + bhh[j + 192];
            float ig = sigm_(a.x), fg = sigm_(a.y), gg = tanh_(a.z), og = sigm_(a.w);
            c = fmaf(fg, c, ig * gg);
            h = og * tanh_(c);
        }
        float last = fmaxf(h, 0.f);
        float acc = rc_val(xb[0]) + bcj;
#pragma unroll
        for (int k = 0; k < 64; ++k)
            acc = fmaf(__shfl(last, k), Wc[jm * 96 + 32 + k], acc);
        comb4 = fmaxf(acc, 0.f);
    } else {
        comb4 = fmaxf(rc_val(xb[0]) + bcj, 0.f);
    }
    float logit = bt[j];
    const float* wtr = Wt + j * 32;
#pragma unroll
    for (int k = 0; k < 32; ++k) logit = fmaf(__shfl(comb4, k), wtr[k], logit);
    float mx = logit;
#pragma unroll
    for (int off = 32; off; off >>= 1) mx = fmaxf(mx, __shfl_xor(mx, off));
    float ex = __expf(logit - mx);
    float sum = ex;
#pragma unroll
    for (int off = 32; off; off >>= 1) sum += __shfl_xor(sum, off);
    out[b * 64 + j] = logit - mx - __logf(sum);
}

extern "C" void kernel_launch(void* const* d_in, const int* in_sizes, int n_in,
                              void* d_out, int out_size, void* d_ws, size_t ws_size,
                              hipStream_t stream) {
    const int* x = (const int*)d_in[0];
    const int* s = (const int*)d_in[1];
    const float* emb = (const float*)d_in[2];
    const float* Wih = (const float*)d_in[3];
    const float* Whh = (const float*)d_in[4];
    const float* bih = (const float*)d_in[5];
    const float* bhh = (const float*)d_in[6];
    const float* h0 = (const float*)d_in[7];
    const float* c0 = (const float*)d_in[8];
    const float* Wc = (const float*)d_in[9];
    const float* bc = (const float*)d_in[10];
    const float* Wt = (const float*)d_in[11];
    const float* bt = (const float*)d_in[12];
    float* out = (float*)d_out;

    // ws layout (16B-aligned chunks)
    size_t off = 0;
    size_t offPp = off;    off += (size_t)NV * 64 * sizeof(float4);   // 32.8 MB
    size_t offRc = off;    off += (size_t)NV * 32 * sizeof(float);    // 4.1 MB
    off = (off + 15) & ~(size_t)15;
    size_t offLv = off;    off += (size_t)NV * 64 * sizeof(float);    // 8.2 MB
    off = (off + 15) & ~(size_t)15;
    size_t offWhhP = off;  off += 4096 * sizeof(float4);
    size_t offWihPk = off; off += 2048 * sizeof(float4);
    size_t offWc2P = off;  off += 512 * sizeof(float4);
    size_t offBsum = off;  off += 64 * sizeof(float4);
    size_t offCnt = off;   off += 16;
    size_t offList = off;  off += (size_t)NB * sizeof(int);
    size_t need = off;

    char* ws = (char*)d_ws;
    if (ws_size >= need) {
        float4* Pp = (float4*)(ws + offPp);
        float* Rc = (float*)(ws + offRc);
        float* Lv = (float*)(ws + offLv);
        float4* WhhP = (float4*)(ws + offWhhP);
        float4* WihPk = (float4*)(ws + offWihPk);
        float4* Wc2P = (float4*)(ws + offWc2P);
        float4* bsumP = (float4*)(ws + offBsum);
        int* cnt = (int*)(ws + offCnt);
        int* list = (int*)(ws + offList);

        hipMemsetAsync(cnt, 0, sizeof(int), stream);
        pre_pack<<<dim3(16), dim3(256), 0, stream>>>(Wih, Whh, bih, bhh, Wc,
                                                     WhhP, WihPk, Wc2P, bsumP);
        pre_tok<<<dim3(8001), dim3(256), 0, stream>>>(emb, WihPk, Wc, bsumP, Pp, Rc);
        pre_light<<<dim3(8001), dim3(256), 0, stream>>>(Rc, bc, Wt, bt, Lv);
        classify<<<dim3(8192), dim3(256), 0, stream>>>(x, s, Lv, cnt, list, out);
        heavy_kernel<<<dim3(4096), dim3(512), 0, stream>>>(
            x, h0, c0, bc, Wt, bt, Pp, Rc, WhhP, WihPk, Wc2P, bsumP, cnt, list, out);
    } else {
        tagger_fallback<<<dim3(4096), dim3(512), 0, stream>>>(
            x, s, emb, Wih, Whh, bih, bhh, h0, c0, Wc, bc, Wt, bt, out);
    }
}

// Round 3
// 286.783 us; speedup vs baseline: 19.2339x; 1.7229x over previous
//
#include <hip/hip_runtime.h>

// Problem constants
#define NB 32768
#define NT 16
#define NV 32001   // V+1
#define NE 32
#define NH 64
#define NTAGS 64

typedef __attribute__((ext_vector_type(8))) short short8;   // 8 bf16 (4 VGPR)
typedef __attribute__((ext_vector_type(4))) float f4;       // MFMA acc

#define MFMA16(a, b, c) __builtin_amdgcn_mfma_f32_16x16x32_bf16(a, b, c, 0, 0, 0)
#define LDSSYNC() asm volatile("s_waitcnt lgkmcnt(0)" ::: "memory")

__device__ __forceinline__ float sigm_(float x) { return 1.0f / (1.0f + __expf(-x)); }
__device__ __forceinline__ float tanh_(float x) {
    x = fminf(fmaxf(x, -15.0f), 15.0f);
    float e = __expf(2.0f * x);
    return (e - 1.0f) / (e + 1.0f);
}
__device__ __forceinline__ short f2bf(float x) {  // RNE float->bf16 bits
    union { float f; unsigned u; } v; v.f = x;
    unsigned r = v.u + 0x7fffu + ((v.u >> 16) & 1u);
    return (short)(r >> 16);
}
__device__ __forceinline__ float bf2f(short s) {
    union { unsigned u; float f; } v; v.u = ((unsigned)(unsigned short)s) << 16;
    return v.f;
}

// ---------------- pack weights: bf16 hi/lo, padded rows for LDS banking ----------------
// wpack: [WhhHi 256x72][WhhLo 256x72][WihHi 256x40] shorts (LDS-staged by heavy kernel)
// wc1[32][32], wc2h/l[32][64], wth[64][32] shorts (read from global/L1), bsum[256] f32
__global__ __launch_bounds__(256) void pre_pack2(
    const float* __restrict__ Wih, const float* __restrict__ Whh,
    const float* __restrict__ bih, const float* __restrict__ bhh,
    const float* __restrict__ Wc, const float* __restrict__ Wt,
    short* __restrict__ wpack, short* __restrict__ wc1,
    short* __restrict__ wc2h, short* __restrict__ wc2l,
    short* __restrict__ wth, float* __restrict__ bsum) {
    int t = blockIdx.x * 256 + threadIdx.x;  // 0..18431
    {   // Whh hi/lo [256][72]
        int r = t / 72, c = t % 72;
        float w = (c < 64) ? Whh[r * 64 + c] : 0.f;
        short hi = f2bf(w);
        wpack[t] = hi;
        wpack[18432 + t] = f2bf(w - bf2f(hi));
    }
    if (t < 10240) {  // Wih hi [256][40]
        int r = t / 40, c = t % 40;
        wpack[36864 + t] = f2bf((c < 32) ? Wih[r * 32 + c] : 0.f);
    }
    if (t < 1024) { int r = t / 32, c = t % 32; wc1[t] = f2bf(Wc[r * 96 + c]); }
    if (t < 2048) {
        int r = t / 64, c = t % 64;
        float w = Wc[r * 96 + 32 + c];
        short hi = f2bf(w); wc2h[t] = hi; wc2l[t] = f2bf(w - bf2f(hi));
    }
    if (t < 2048) { int r = t / 32, c = t % 32; wth[t] = f2bf(Wt[r * 32 + c]); }
    if (t < 256) bsum[t] = bih[t] + bhh[t];
}

// ---------------- emb -> bf16 hi table ----------------
__global__ __launch_bounds__(512) void pre_emb(const float* __restrict__ emb,
                                               short* __restrict__ eh) {
    int i = blockIdx.x * 512 + threadIdx.x;
    if (i < NV * NE) eh[i] = f2bf(emb[i]);
}

// ---------------- light table: Lv[v] = log_softmax(relu(emb[v]@Wc1^T+bc)@Wt^T+bt) ----------------
__global__ __launch_bounds__(256) void pre_light(const float* __restrict__ emb,
                                                 const float* __restrict__ Wc,
                                                 const float* __restrict__ bc,
                                                 const float* __restrict__ Wt,
                                                 const float* __restrict__ bt,
                                                 float* __restrict__ Lv) {
    int wave = threadIdx.x >> 6, j = threadIdx.x & 63, jm = j & 31;
    int v = blockIdx.x * 4 + wave;
    if (v >= NV) return;
    const float* ev = emb + v * NE;
    float r = 0.f;
#pragma unroll
    for (int k = 0; k < 32; ++k) r = fmaf(ev[k], Wc[jm * 96 + k], r);
    float comb = fmaxf(r + bc[jm], 0.f);
    float logit = bt[j];
    const float* wtr = Wt + j * 32;
#pragma unroll
    for (int k = 0; k < 32; ++k) logit = fmaf(__shfl(comb, k), wtr[k], logit);
    float mx = logit;
#pragma unroll
    for (int off = 32; off; off >>= 1) mx = fmaxf(mx, __shfl_xor(mx, off));
    float ex = __expf(logit - mx);
    float sum = ex;
#pragma unroll
    for (int off = 32; off; off >>= 1) sum += __shfl_xor(sum, off);
    Lv[v * 64 + j] = logit - mx - __logf(sum);
}

// ---------------- classify: 1 thread/row, 1 atomic/block (32 total) ----------------
__global__ __launch_bounds__(1024) void classify_list(const int* __restrict__ s,
                                                      int* __restrict__ cnt,
                                                      int* __restrict__ list) {
    __shared__ int wbase[16];
    __shared__ int blkbase;
    int tid = threadIdx.x;
    int row = blockIdx.x * 1024 + tid;  // grid 32*1024 == NB exactly
    bool heavy = s[row] >= 4;
    unsigned long long mask = __ballot(heavy);
    int wv = tid >> 6, lane = tid & 63;
    if (lane == 0) wbase[wv] = __popcll(mask);
    __syncthreads();
    if (tid == 0) {
        int tot = 0;
#pragma unroll
        for (int i = 0; i < 16; ++i) { int c = wbase[i]; wbase[i] = tot; tot += c; }
        blkbase = atomicAdd(cnt, tot);
    }
    __syncthreads();
    if (heavy) {
        int pos = blkbase + wbase[wv] + __popcll(mask & ((1ull << lane) - 1ull));
        list[pos] = row;
    }
}

// ---------------- light rows: out = Lv[x0] ----------------
__global__ __launch_bounds__(256) void light_out(const int* __restrict__ x,
                                                 const int* __restrict__ s,
                                                 const float* __restrict__ Lv,
                                                 float* __restrict__ out) {
    int gw = (blockIdx.x * 256 + threadIdx.x) >> 6;
    int j = threadIdx.x & 63;
    if (s[gw] < 4) out[gw * 64 + j] = Lv[x[gw * 16] * 64 + j];
}

// ---------------- heavy: MFMA tree-LSTM, 1 wave = 4 rows x (4 nodes || node4) ----------------
__global__ __launch_bounds__(512, 2) void heavy_mfma(
    const int* __restrict__ x,
    const float* __restrict__ h0, const float* __restrict__ c0,
    const float* __restrict__ bc, const float* __restrict__ bt,
    const float* __restrict__ bsum,
    const short* __restrict__ wpack, const short* __restrict__ wc1,
    const short* __restrict__ wc2h, const short* __restrict__ wc2l,
    const short* __restrict__ wth, const short* __restrict__ embH,
    const int* __restrict__ cnt, const int* __restrict__ list,
    float* __restrict__ out) {
    __shared__ __align__(16) short sW[47104];      // WhhHi[256*72] WhhLo[256*72] WihHi[256*40]
    __shared__ __align__(16) float sH[8][1088];    // per-wave h stage [16 units][68]
    __shared__ __align__(16) short sCmb[8][1280];  // per-wave comb hi[640] lo[640]: [node][rloc][40]
    __shared__ __align__(16) short sC4[8][320];    // per-wave comb4 hi[160] lo[160]: [rloc][40]

    const int nheavy = *cnt;
    if (blockIdx.x * 32 >= nheavy) return;

    for (int i = threadIdx.x; i < 5888; i += 512)
        ((uint4*)sW)[i] = ((const uint4*)wpack)[i];
    __syncthreads();

    const short* sWhhHi = sW;
    const short* sWhhLo = sW + 18432;
    const short* sWihH = sW + 36864;

    const int wave = threadIdx.x >> 6;
    const int lane = threadIdx.x & 63;
    const int q = lane >> 4;   // quad (= node in phase-1 epilogue; A k-group)
    const int n = lane & 15;   // MFMA n / A-row m
    float* hst = sH[wave];
    short* cmbH = sCmb[wave];
    short* cmbL = cmbH + 640;
    short* c4H = sC4[wave];
    short* c4L = c4H + 160;

    // preloads (all L2/L1-hot broadcasts)
    float bias16[16];
#pragma unroll
    for (int tl = 0; tl < 16; ++tl) bias16[tl] = bsum[tl * 16 + n];
    float bc2[2] = {bc[n], bc[16 + n]};
    float bt4[4] = {bt[n], bt[16 + n], bt[32 + n], bt[48 + n]};
    float h0v[4], c0v[4];
#pragma unroll
    for (int u = 0; u < 4; ++u) { h0v[u] = h0[u * 16 + n]; c0v[u] = c0[u * 16 + n]; }

    const int strideRows = gridDim.x * 32;
#pragma unroll 1
    for (int base = (blockIdx.x * 8 + wave) * 4; base < nheavy; base += strideRows) {
        const int rid = base + q;
        const int row = list[min(rid, nheavy - 1)];
        const int tokAll = x[row * 16 + n];  // lane (q,n) holds x[row_q][n]

        f4 acc[16];
        float cst[4][4];
        short8 a_root;

        // helper lambdas --------------------------------------------------
        auto loadAh = [&](int kh, short8& hi8, short8& lo8) {
            const f4* hp = (const f4*)&hst[n * 68 + kh * 32 + q * 8];
            f4 x0 = hp[0], x1 = hp[1];
            float xs[8] = {x0[0], x0[1], x0[2], x0[3], x1[0], x1[1], x1[2], x1[3]};
#pragma unroll
            for (int e = 0; e < 8; ++e) {
                short hb = f2bf(xs[e]);
                hi8[e] = hb;
                lo8[e] = f2bf(xs[e] - bf2f(hb));
            }
        };
        auto recurrent = [&]() {
            short8 ah0, al0, ah1, al1;
            loadAh(0, ah0, al0);
            loadAh(1, ah1, al1);
#pragma unroll
            for (int tl = 0; tl < 16; ++tl) {
                const int rb = (tl * 16 + n) * 72 + q * 8;
                short8 bh0 = *(const short8*)&sWhhHi[rb];
                short8 bl0 = *(const short8*)&sWhhLo[rb];
                short8 bh1 = *(const short8*)&sWhhHi[rb + 32];
                short8 bl1 = *(const short8*)&sWhhLo[rb + 32];
                f4 t0 = acc[tl];
                t0 = MFMA16(ah0, bh0, t0);
                t0 = MFMA16(al0, bh0, t0);
                t0 = MFMA16(ah0, bl0, t0);
                t0 = MFMA16(ah1, bh1, t0);
                t0 = MFMA16(al1, bh1, t0);
                t0 = MFMA16(ah1, bl1, t0);
                acc[tl] = t0;
            }
        };
        auto epilogue = [&](bool reluOut) {
            LDSSYNC();
#pragma unroll
            for (int u = 0; u < 4; ++u)
#pragma unroll
                for (int r = 0; r < 4; ++r) {
                    float ip = acc[u][r], fp = acc[4 + u][r];
                    float gp = acc[8 + u][r], op = acc[12 + u][r];
                    float cc = fmaf(sigm_(fp), cst[r][u], sigm_(ip) * tanh_(gp));
                    cst[r][u] = cc;
                    float hh = sigm_(op) * tanh_(cc);
                    hst[(4 * q + r) * 68 + u * 16 + n] = reluOut ? fmaxf(hh, 0.f) : hh;
                }
            LDSSYNC();
        };
        auto initState = [&]() {
#pragma unroll
            for (int u = 0; u < 4; ++u)
#pragma unroll
                for (int r = 0; r < 4; ++r) {
                    cst[r][u] = c0v[u];
                    hst[(4 * q + r) * 68 + u * 16 + n] = h0v[u];
                }
            LDSSYNC();
        };
        auto combMM = [&](const short8& aroot, f4* acc2) {
            acc2[0] = f4{bc2[0], bc2[0], bc2[0], bc2[0]};
            acc2[1] = f4{bc2[1], bc2[1], bc2[1], bc2[1]};
            short8 lh0, ll0, lh1, ll1;  // relu(h_last) frags from stage
            loadAh(0, lh0, ll0);
            loadAh(1, lh1, ll1);
#pragma unroll
            for (int tl2 = 0; tl2 < 2; ++tl2) {
                short8 b1 = *(const short8*)&wc1[(tl2 * 16 + n) * 32 + q * 8];
                f4 t0 = MFMA16(aroot, b1, acc2[tl2]);
                const int rb = (tl2 * 16 + n) * 64 + q * 8;
                short8 bh0 = *(const short8*)&wc2h[rb];
                short8 bl0 = *(const short8*)&wc2l[rb];
                short8 bh1 = *(const short8*)&wc2h[rb + 32];
                short8 bl1 = *(const short8*)&wc2l[rb + 32];
                t0 = MFMA16(lh0, bh0, t0);
                t0 = MFMA16(ll0, bh0, t0);
                t0 = MFMA16(lh0, bl0, t0);
                t0 = MFMA16(lh1, bh1, t0);
                t0 = MFMA16(ll1, bh1, t0);
                t0 = MFMA16(lh1, bl1, t0);
                acc2[tl2] = t0;
            }
        };

        // ---- phase 1: nodes 0..3 in parallel (unit m = node*4 + rloc) ----
        initState();
#pragma unroll 1
        for (int t = 0; t < 4; ++t) {
            int li = (n & 3) * 16 + (n >> 2) * 4 + t;  // lane holding x[row_{n&3}][(n>>2)*4+t]
            int tok = __shfl(tokAll, li);
            short8 a_e = *(const short8*)&embH[tok * 32 + q * 8];
            if (t == 0) a_root = a_e;
#pragma unroll
            for (int tl = 0; tl < 16; ++tl)
                acc[tl] = f4{bias16[tl], bias16[tl], bias16[tl], bias16[tl]};
            recurrent();
#pragma unroll
            for (int tl = 0; tl < 16; ++tl) {
                short8 bW = *(const short8*)&sWihH[(tl * 16 + n) * 40 + q * 8];
                acc[tl] = MFMA16(a_e, bW, acc[tl]);
            }
            epilogue(t == 3);  // write relu(h3) at final step (= "last")
        }
        {   // comb for nodes 0..3 -> LDS (node = q, rloc = reg)
            f4 acc2[2];
            combMM(a_root, acc2);
#pragma unroll
            for (int tl2 = 0; tl2 < 2; ++tl2)
#pragma unroll
                for (int r = 0; r < 4; ++r) {
                    float cv = fmaxf(acc2[tl2][r], 0.f);
                    int ci = (q * 4 + r) * 40 + tl2 * 16 + n;
                    short hb = f2bf(cv);
                    cmbH[ci] = hb;
                    cmbL[ci] = f2bf(cv - bf2f(hb));
                }
            LDSSYNC();
        }

        // ---- phase 2: node 4 (children = comb_0..3); rows duplicated across quads ----
        initState();
        int tok4 = __shfl(tokAll, (n & 3) * 16);  // x[row_{n&3}][0]
        short8 a_r4 = *(const short8*)&embH[tok4 * 32 + q * 8];
#pragma unroll 1
        for (int t = 0; t < 4; ++t) {
            const int cb = (t * 4 + (n & 3)) * 40 + q * 8;
            short8 ach = *(const short8*)&cmbH[cb];
            short8 acl = *(const short8*)&cmbL[cb];
#pragma unroll
            for (int tl = 0; tl < 16; ++tl)
                acc[tl] = f4{bias16[tl], bias16[tl], bias16[tl], bias16[tl]};
            recurrent();
#pragma unroll
            for (int tl = 0; tl < 16; ++tl) {
                short8 bW = *(const short8*)&sWihH[(tl * 16 + n) * 40 + q * 8];
                f4 t0 = MFMA16(ach, bW, acc[tl]);
                acc[tl] = MFMA16(acl, bW, t0);
            }
            epilogue(t == 3);
        }
        {   // comb4 -> LDS [rloc][40] (all quads write identical values)
            f4 acc2[2];
            combMM(a_r4, acc2);
#pragma unroll
            for (int tl2 = 0; tl2 < 2; ++tl2)
#pragma unroll
                for (int r = 0; r < 4; ++r) {
                    float cv = fmaxf(acc2[tl2][r], 0.f);
                    int ci = r * 40 + tl2 * 16 + n;
                    short hb = f2bf(cv);
                    c4H[ci] = hb;
                    c4L[ci] = f2bf(cv - bf2f(hb));
                }
            LDSSYNC();
        }

        // ---- phase 3: logits + log_softmax ----
        {
            const int cb = (n & 3) * 40 + q * 8;
            short8 c4h = *(const short8*)&c4H[cb];
            short8 c4l = *(const short8*)&c4L[cb];
            f4 acc3[4];
#pragma unroll
            for (int tl3 = 0; tl3 < 4; ++tl3) {
                f4 t0 = f4{bt4[tl3], bt4[tl3], bt4[tl3], bt4[tl3]};
                short8 bW = *(const short8*)&wth[(tl3 * 16 + n) * 32 + q * 8];
                t0 = MFMA16(c4h, bW, t0);
                acc3[tl3] = MFMA16(c4l, bW, t0);
            }
            // every lane holds logits[row=r][g=tl3*16+n] in acc3[tl3][r]
#pragma unroll
            for (int r = 0; r < 4; ++r) {
                float l0 = acc3[0][r], l1 = acc3[1][r], l2 = acc3[2][r], l3 = acc3[3][r];
                float mx = fmaxf(fmaxf(l0, l1), fmaxf(l2, l3));
#pragma unroll
                for (int off = 8; off; off >>= 1) mx = fmaxf(mx, __shfl_xor(mx, off));
                float sm = __expf(l0 - mx) + __expf(l1 - mx) + __expf(l2 - mx) + __expf(l3 - mx);
#pragma unroll
                for (int off = 8; off; off >>= 1) sm += __shfl_xor(sm, off);
                float lse = mx + __logf(sm);
                if (q == r && base + r < nheavy) {
                    out[row * 64 + n] = l0 - lse;
                    out[row * 64 + 16 + n] = l1 - lse;
                    out[row * 64 + 32 + n] = l2 - lse;
                    out[row * 64 + 48 + n] = l3 - lse;
                }
            }
        }
    }
}

// ---------------- fallback (small ws): round-2 monolithic kernel ----------------
__global__ __launch_bounds__(512) void tagger_fallback(
    const int* __restrict__ x, const int* __restrict__ s, const float* __restrict__ emb,
    const float* __restrict__ Wih, const float* __restrict__ Whh,
    const float* __restrict__ bih, const float* __restrict__ bhh,
    const float* __restrict__ h0, const float* __restrict__ c0,
    const float* __restrict__ Wc, const float* __restrict__ bc,
    const float* __restrict__ Wt, const float* __restrict__ bt,
    float* __restrict__ out) {
    __shared__ float4 WhhP[4096];
    __shared__ float combBuf[8][128];
    for (int i = threadIdx.x; i < 4096; i += 512) {
        int k = i & 63, jj = i >> 6;
        WhhP[k * 64 + jj] = make_float4(Whh[jj * 64 + k], Whh[(jj + 64) * 64 + k],
                                        Whh[(jj + 128) * 64 + k], Whh[(jj + 192) * 64 + k]);
    }
    __syncthreads();
    const int wave = threadIdx.x >> 6, j = threadIdx.x & 63, jm = j & 31;
    const int b = blockIdx.x * 8 + wave;
    const int sv = s[b];
    const int* xb = x + b * NT;
    const float bcj = bc[jm];
    auto rc_val = [&](int tok) -> float {
        float r = 0.f;
#pragma unroll
        for (int k = 0; k < 32; ++k) r = fmaf(emb[tok * NE + k], Wc[jm * 96 + k], r);
        return r;
    };
    float comb4;
    if (sv >= 4) {
        const float h0j = h0[j], c0j = c0[j];
        float4 bsj = make_float4(bih[j] + bhh[j], bih[j + 64] + bhh[j + 64],
                                 bih[j + 128] + bhh[j + 128], bih[j + 192] + bhh[j + 192]);
#pragma unroll 1
        for (int node = 0; node < 4; ++node) {
            float h = h0j, c = c0j;
#pragma unroll 1
            for (int t = 0; t < 4; ++t) {
                int tok = xb[node * 4 + t];
                float4 p = bsj;
#pragma unroll
                for (int k = 0; k < 32; ++k) {
                    float e = emb[tok * NE + k];
                    p.x = fmaf(e, Wih[j * 32 + k], p.x);
                    p.y = fmaf(e, Wih[(j + 64) * 32 + k], p.y);
                    p.z = fmaf(e, Wih[(j + 128) * 32 + k], p.z);
                    p.w = fmaf(e, Wih[(j + 192) * 32 + k], p.w);
                }
                float4 a = make_float4(0.f, 0.f, 0.f, 0.f);
#pragma unroll
                for (int k = 0; k < 64; ++k) {
                    float hk = __shfl(h, k);
                    float4 w = WhhP[k * 64 + j];
                    a.x = fmaf(hk, w.x, a.x); a.y = fmaf(hk, w.y, a.y);
                    a.z = fmaf(hk, w.z, a.z); a.w = fmaf(hk, w.w, a.w);
                }
                a.x += p.x; a.y += p.y; a.z += p.z; a.w += p.w;
                float ig = sigm_(a.x), fg = sigm_(a.y), gg = tanh_(a.z), og = sigm_(a.w);
                c = fmaf(fg, c, ig * gg);
                h = og * tanh_(c);
            }
            float last = fmaxf(h, 0.f);
            float acc = rc_val(xb[node * 4]) + bcj;
#pragma unroll
            for (int k = 0; k < 64; ++k)
                acc = fmaf(__shfl(last, k), Wc[jm * 96 + 32 + k], acc);
            if (j < 32) combBuf[wave][node * 32 + j] = fmaxf(acc, 0.f);
        }
        LDSSYNC();
        float h = h0j, c = c0j;
#pragma unroll 1
        for (int t = 0; t < 4; ++t) {
            float4 a = make_float4(0.f, 0.f, 0.f, 0.f);
#pragma unroll
            for (int k = 0; k < 32; ++k) {
                float ck = combBuf[wave][t * 32 + k];
                a.x = fmaf(ck, Wih[j * 32 + k], a.x);
                a.y = fmaf(ck, Wih[(j + 64) * 32 + k], a.y);
                a.z = fmaf(ck, Wih[(j + 128) * 32 + k], a.z);
                a.w = fmaf(ck, Wih[(j + 192) * 32 + k], a.w);
            }
#pragma unroll
            for (int k = 0; k < 64; ++k) {
                float hk = __shfl(h, k);
                float4 w = WhhP[k * 64 + j];
                a.x = fmaf(hk, w.x, a.x); a.y = fmaf(hk, w.y, a.y);
                a.z = fmaf(hk, w.z, a.z); a.w = fmaf(hk, w.w, a.w);
            }
            a.x += bih[j] + bhh[j]; a.y += bih[j + 64] + bhh[j + 64];
            a.z += bih[j + 128] + bhh[j + 128]; a.w += bih[j + 192] + bhh[j + 192];
            float ig = sigm_(a.x), fg = sigm_(a.y), gg = tanh_(a.z), og = sigm_(a.w);
            c = fmaf(fg, c, ig * gg);
            h = og * tanh_(c);
        }
        float last = fmaxf(h, 0.f);
        float acc = rc_val(xb[0]) + bcj;
#pragma unroll
        for (int k = 0; k < 64; ++k)
            acc = fmaf(__shfl(last, k), Wc[jm * 96 + 32 + k], acc);
        comb4 = fmaxf(acc, 0.f);
    } else {
        comb4 = fmaxf(rc_val(xb[0]) + bcj, 0.f);
    }
    float logit = bt[j];
    const float* wtr = Wt + j * 32;
#pragma unroll
    for (int k = 0; k < 32; ++k) logit = fmaf(__shfl(comb4, k), wtr[k], logit);
    float mx = logit;
#pragma unroll
    for (int off = 32; off; off >>= 1) mx = fmaxf(mx, __shfl_xor(mx, off));
    float ex = __expf(logit - mx);
    float sum = ex;
#pragma unroll
    for (int off = 32; off; off >>= 1) sum += __shfl_xor(sum, off);
    out[b * 64 + j] = logit - mx - __logf(sum);
}

extern "C" void kernel_launch(void* const* d_in, const int* in_sizes, int n_in,
                              void* d_out, int out_size, void* d_ws, size_t ws_size,
                              hipStream_t stream) {
    const int* x = (const int*)d_in[0];
    const int* s = (const int*)d_in[1];
    const float* emb = (const float*)d_in[2];
    const float* Wih = (const float*)d_in[3];
    const float* Whh = (const float*)d_in[4];
    const float* bih = (const float*)d_in[5];
    const float* bhh = (const float*)d_in[6];
    const float* h0 = (const float*)d_in[7];
    const float* c0 = (const float*)d_in[8];
    const float* Wc = (const float*)d_in[9];
    const float* bc = (const float*)d_in[10];
    const float* Wt = (const float*)d_in[11];
    const float* bt = (const float*)d_in[12];
    float* out = (float*)d_out;

    auto al16 = [](size_t v) { return (v + 15) & ~(size_t)15; };
    size_t off = 0;
    size_t oWpack = off; off = al16(off + 47104 * 2);
    size_t oWc1 = off;   off = al16(off + 1024 * 2);
    size_t oWc2h = off;  off = al16(off + 2048 * 2);
    size_t oWc2l = off;  off = al16(off + 2048 * 2);
    size_t oWt = off;    off = al16(off + 2048 * 2);
    size_t oBsum = off;  off = al16(off + 256 * 4);
    size_t oEmbH = off;  off = al16(off + (size_t)NV * 32 * 2);
    size_t oLv = off;    off = al16(off + (size_t)NV * 64 * 4);
    size_t oCnt = off;   off = al16(off + 16);
    size_t oList = off;  off = al16(off + (size_t)NB * 4);
    size_t need = off;

    char* ws = (char*)d_ws;
    if (ws_size >= need) {
        short* wpack = (short*)(ws + oWpack);
        short* wc1 = (short*)(ws + oWc1);
        short* wc2h = (short*)(ws + oWc2h);
        short* wc2l = (short*)(ws + oWc2l);
        short* wth = (short*)(ws + oWt);
        float* bsum = (float*)(ws + oBsum);
        short* embH = (short*)(ws + oEmbH);
        float* Lv = (float*)(ws + oLv);
        int* cnt = (int*)(ws + oCnt);
        int* list = (int*)(ws + oList);

        hipMemsetAsync(cnt, 0, sizeof(int), stream);
        pre_pack2<<<dim3(72), dim3(256), 0, stream>>>(Wih, Whh, bih, bhh, Wc, Wt,
                                                      wpack, wc1, wc2h, wc2l, wth, bsum);
        pre_emb<<<dim3(2001), dim3(512), 0, stream>>>(emb, embH);
        pre_light<<<dim3(8001), dim3(256), 0, stream>>>(emb, Wc, bc, Wt, bt, Lv);
        classify_list<<<dim3(32), dim3(1024), 0, stream>>>(s, cnt, list);
        light_out<<<dim3(8192), dim3(256), 0, stream>>>(x, s, Lv, out);
        heavy_mfma<<<dim3(320), dim3(512), 0, stream>>>(
            x, h0, c0, bc, bt, bsum, wpack, wc1, wc2h, wc2l, wth, embH, cnt, list, out);
    } else {
        tagger_fallback<<<dim3(4096), dim3(512), 0, stream>>>(
            x, s, emb, Wih, Whh, bih, bhh, h0, c0, Wc, bc, Wt, bt, out);
    }
}

// Round 4
// 209.805 us; speedup vs baseline: 26.2909x; 1.3669x over previous
//
#include <hip/hip_runtime.h>

// Problem constants
#define NB 32768
#define NT 16
#define NV 32001   // V+1
#define NE 32
#define NTAGS 64

typedef __attribute__((ext_vector_type(8))) short short8;   // 8 bf16 (4 VGPR)
typedef __attribute__((ext_vector_type(4))) float f4;       // MFMA acc

#define MFMA16(a, b, c) __builtin_amdgcn_mfma_f32_16x16x32_bf16(a, b, c, 0, 0, 0)
// DS ops are in-order within a wave -> compiler-only fence suffices for LDS RAW/WAR
#define CFENCE() asm volatile("" ::: "memory")
#define LDSSYNC() asm volatile("s_waitcnt lgkmcnt(0)" ::: "memory")

__device__ __forceinline__ float sigm_(float x) { return 1.0f / (1.0f + __expf(-x)); }
__device__ __forceinline__ float tanh_(float x) {
    x = fminf(fmaxf(x, -15.0f), 15.0f);
    float e = __expf(2.0f * x);
    return (e - 1.0f) / (e + 1.0f);
}
__device__ __forceinline__ short f2bf(float x) {  // RNE float->bf16 bits
    union { float f; unsigned u; } v; v.f = x;
    unsigned r = v.u + 0x7fffu + ((v.u >> 16) & 1u);
    return (short)(r >> 16);
}

// ---------------- K1: fused prep (emb->bf16 + weight pack, hi-only) ----------------
// wpack: [WhhHi 256x72][WihHi 256x40] shorts; wc1[32][32], wc2[32][64], wth[64][32]; bsum[256] f32
__global__ __launch_bounds__(256) void prep(
    const float* __restrict__ emb, const float* __restrict__ Wih,
    const float* __restrict__ Whh, const float* __restrict__ bih,
    const float* __restrict__ bhh, const float* __restrict__ Wc,
    const float* __restrict__ Wt,
    short* __restrict__ embH, short* __restrict__ wpack, short* __restrict__ wc1,
    short* __restrict__ wc2, short* __restrict__ wth, float* __restrict__ bsum) {
    int b = blockIdx.x, tid = threadIdx.x;
    if (b < 4001) {
        int i = b * 256 + tid;
        if (i < NV * NE) embH[i] = f2bf(emb[i]);
    } else {
        int t = (b - 4001) * 256 + tid;  // 0..18431
        { int r = t / 72, c = t % 72;
          wpack[t] = f2bf(c < 64 ? Whh[r * 64 + c] : 0.f); }
        if (t < 10240) { int r = t / 40, c = t % 40;
          wpack[18432 + t] = f2bf(c < 32 ? Wih[r * 32 + c] : 0.f); }
        if (t < 1024) { int r = t >> 5, c = t & 31; wc1[t] = f2bf(Wc[r * 96 + c]); }
        if (t < 2048) { int r = t >> 6, c = t & 63; wc2[t] = f2bf(Wc[r * 96 + 32 + c]); }
        if (t < 2048) { int r = t >> 5, c = t & 31; wth[t] = f2bf(Wt[r * 32 + c]); }
        if (t < 256) bsum[t] = bih[t] + bhh[t];
    }
}

// ---------------- K2: classify, 1 atomic/block (32 total) ----------------
__global__ __launch_bounds__(1024) void classify_list(const int* __restrict__ s,
                                                      int* __restrict__ cnt,
                                                      int* __restrict__ list) {
    __shared__ int wbase[16];
    __shared__ int blkbase;
    int tid = threadIdx.x;
    int row = blockIdx.x * 1024 + tid;  // 32*1024 == NB
    bool heavy = s[row] >= 4;
    unsigned long long mask = __ballot(heavy);
    int wv = tid >> 6, lane = tid & 63;
    if (lane == 0) wbase[wv] = __popcll(mask);
    __syncthreads();
    if (tid == 0) {
        int tot = 0;
#pragma unroll
        for (int i = 0; i < 16; ++i) { int c = wbase[i]; wbase[i] = tot; tot += c; }
        blkbase = atomicAdd(cnt, tot);
    }
    __syncthreads();
    if (heavy) {
        int pos = blkbase + wbase[wv] + __popcll(mask & ((1ull << lane) - 1ull));
        list[pos] = row;
    }
}

// ---------------- K3: fused main — heavy rows (MFMA) + light rows ----------------
__global__ __launch_bounds__(256, 3) void main_fused(
    const int* __restrict__ x, const int* __restrict__ s,
    const float* __restrict__ emb, const float* __restrict__ h0,
    const float* __restrict__ c0, const float* __restrict__ Wc,
    const float* __restrict__ bc, const float* __restrict__ Wt,
    const float* __restrict__ bt, const float* __restrict__ bsum,
    const short* __restrict__ wpack, const short* __restrict__ wc1,
    const short* __restrict__ wc2, const short* __restrict__ wth,
    const short* __restrict__ embH,
    const int* __restrict__ cnt, const int* __restrict__ list,
    float* __restrict__ out) {
    __shared__ __align__(16) short sWhh[18432];      // 36 KB [256][72]
    __shared__ __align__(16) short sHA[4][16 * 72];  // per-wave h (A-frag layout, bf16)
    __shared__ __align__(16) short sCmb[4][16 * 40]; // per-wave comb_0..3
    __shared__ __align__(16) short sC4[4][4 * 40];   // per-wave comb4

    for (int i = threadIdx.x; i < 1152; i += 256)
        ((uint4*)sWhh)[i] = ((const uint4*)wpack)[i];
    __syncthreads();

    const int wave = threadIdx.x >> 6, lane = threadIdx.x & 63;
    const int q = lane >> 4;   // quad
    const int n = lane & 15;   // MFMA m/n index
    const int gw = blockIdx.x * 4 + wave;  // 0..3071
    const int nheavy = *cnt;
    short* hA = sHA[wave];
    short* cmb = sCmb[wave];
    short* c4 = sC4[wave];
    const short* wihG = wpack + 18432;  // [256][40] bf16, L1/L2-hot

    // preloads (broadcast / L1-hot)
    float bias16[16];
#pragma unroll
    for (int tl = 0; tl < 16; ++tl) bias16[tl] = bsum[tl * 16 + n];
    float bc2[2] = {bc[n], bc[16 + n]};
    float bt4[4] = {bt[n], bt[16 + n], bt[32 + n], bt[48 + n]};
    float c0v[4];
    short h0b[4];
#pragma unroll
    for (int u = 0; u < 4; ++u) { c0v[u] = c0[u * 16 + n]; h0b[u] = f2bf(h0[u * 16 + n]); }

    const f4 zero4 = {0.f, 0.f, 0.f, 0.f};
    f4 acc[16];
    float cst[4][4];

    auto initState = [&]() {
#pragma unroll
        for (int u = 0; u < 4; ++u) {
            short hb = h0b[u];
#pragma unroll
            for (int r = 0; r < 4; ++r) {
                cst[r][u] = c0v[u];
                hA[(4 * q + r) * 72 + u * 16 + n] = hb;
            }
        }
        CFENCE();
    };
    // one LSTM step for 16 units: proj(aP) + Whh*h + bias -> gates -> h into hA (bf16)
    auto step = [&](short8 aP, bool doRelu) {
#pragma unroll
        for (int tl = 0; tl < 16; ++tl) {
            short8 bW = *(const short8*)&wihG[(tl * 16 + n) * 40 + q * 8];
            acc[tl] = MFMA16(aP, bW, zero4);
        }
        short8 ah0 = *(const short8*)&hA[n * 72 + q * 8];
        short8 ah1 = *(const short8*)&hA[n * 72 + 32 + q * 8];
#pragma unroll
        for (int tl = 0; tl < 16; ++tl) {
            const short* rbp = &sWhh[(tl * 16 + n) * 72 + q * 8];
            f4 t0 = acc[tl];
            t0 = MFMA16(ah0, *(const short8*)rbp, t0);
            t0 = MFMA16(ah1, *(const short8*)(rbp + 32), t0);
            acc[tl] = t0;
        }
        CFENCE();
#pragma unroll
        for (int u = 0; u < 4; ++u)
#pragma unroll
            for (int r = 0; r < 4; ++r) {
                float ip = acc[u][r] + bias16[u];
                float fp = acc[4 + u][r] + bias16[4 + u];
                float gp = acc[8 + u][r] + bias16[8 + u];
                float op = acc[12 + u][r] + bias16[12 + u];
                float cc = fmaf(sigm_(fp), cst[r][u], sigm_(ip) * tanh_(gp));
                cst[r][u] = cc;
                float hh = sigm_(op) * tanh_(cc);
                if (doRelu) hh = fmaxf(hh, 0.f);
                hA[(4 * q + r) * 72 + u * 16 + n] = f2bf(hh);
            }
        CFENCE();
    };
    // comb = relu([root, last] @ Wc^T + bc): 32-dim result per unit -> dst (bf16)
    auto combMM = [&](short8 aroot, short* dst, bool perQuad) {
        short8 lh0 = *(const short8*)&hA[n * 72 + q * 8];
        short8 lh1 = *(const short8*)&hA[n * 72 + 32 + q * 8];
#pragma unroll
        for (int tl2 = 0; tl2 < 2; ++tl2) {
            f4 t0 = {bc2[tl2], bc2[tl2], bc2[tl2], bc2[tl2]};
            short8 b1 = *(const short8*)&wc1[(tl2 * 16 + n) * 32 + q * 8];
            t0 = MFMA16(aroot, b1, t0);
            const short* rbp = &wc2[(tl2 * 16 + n) * 64 + q * 8];
            t0 = MFMA16(lh0, *(const short8*)rbp, t0);
            t0 = MFMA16(lh1, *(const short8*)(rbp + 32), t0);
#pragma unroll
            for (int r = 0; r < 4; ++r) {
                int rowi = perQuad ? (q * 4 + r) : r;  // phase2: 4 quads write same data
                dst[rowi * 40 + tl2 * 16 + n] = f2bf(fmaxf(t0[r], 0.f));
            }
        }
        CFENCE();
    };

    // ---- heavy iterations: 1 wave = 4 rows; units = 4 rows x 4 nodes ----
#pragma unroll 1
    for (int it = gw; it * 4 < nheavy; it += 3072) {
        const int base = it * 4;
        const int rid = base + q;
        const int row = list[min(rid, nheavy - 1)];
        const int tokAll = x[row * 16 + n];  // lane (q,n) holds x[row_q][n]
        const int liBase = (n & 3) * 16 + (n >> 2) * 4;  // lane of x[row_{n&3}][(n>>2)*4 + t]

        // phase 1: nodes 0..3 in parallel
        initState();
        short8 aNext, aRoot;
        { int tok = __shfl(tokAll, liBase);
          aNext = *(const short8*)&embH[tok * 32 + q * 8]; }
        aRoot = aNext;
#pragma unroll 1
        for (int t = 0; t < 4; ++t) {
            short8 aP = aNext;
            if (t < 3) {  // prefetch next emb frag (latency hidden behind step)
                int tok = __shfl(tokAll, liBase + t + 1);
                aNext = *(const short8*)&embH[tok * 32 + q * 8];
            }
            step(aP, t == 3);  // step 3 writes relu(h) = "last"
        }
        combMM(aRoot, cmb, true);

        // phase 2: node 4, children = comb_0..3 (rows duplicated across quads)
        initState();
        int tok4 = __shfl(tokAll, (n & 3) * 16);
        short8 aR4 = *(const short8*)&embH[tok4 * 32 + q * 8];
#pragma unroll 1
        for (int t = 0; t < 4; ++t) {
            short8 aC = *(const short8*)&cmb[(t * 4 + (n & 3)) * 40 + q * 8];
            step(aC, t == 3);
        }
        combMM(aR4, c4, false);

        // phase 3: logits + log_softmax for 4 rows
        {
            short8 cA = *(const short8*)&c4[(n & 3) * 40 + q * 8];
            f4 a3[4];
#pragma unroll
            for (int tl3 = 0; tl3 < 4; ++tl3) {
                f4 t0 = {bt4[tl3], bt4[tl3], bt4[tl3], bt4[tl3]};
                short8 bW = *(const short8*)&wth[(tl3 * 16 + n) * 32 + q * 8];
                a3[tl3] = MFMA16(cA, bW, t0);
            }
#pragma unroll
            for (int r = 0; r < 4; ++r) {
                float l0 = a3[0][r], l1 = a3[1][r], l2 = a3[2][r], l3 = a3[3][r];
                float mx = fmaxf(fmaxf(l0, l1), fmaxf(l2, l3));
#pragma unroll
                for (int off = 8; off; off >>= 1) mx = fmaxf(mx, __shfl_xor(mx, off));
                float sm = __expf(l0 - mx) + __expf(l1 - mx) +
                           __expf(l2 - mx) + __expf(l3 - mx);
#pragma unroll
                for (int off = 8; off; off >>= 1) sm += __shfl_xor(sm, off);
                float lse = mx + __logf(sm);
                if (q == r && rid < nheavy) {
                    out[row * 64 + n] = l0 - lse;
                    out[row * 64 + 16 + n] = l1 - lse;
                    out[row * 64 + 32 + n] = l2 - lse;
                    out[row * 64 + 48 + n] = l3 - lse;
                }
            }
        }
    }

    // ---- light rows: out depends only on x[row][0] (last==0 when s<4) ----
    const int jm = lane & 31;
    float wcr[32], wtr[32];
#pragma unroll
    for (int k4 = 0; k4 < 8; ++k4) {
        f4 wv = *(const f4*)&Wc[jm * 96 + k4 * 4];
        wcr[4 * k4] = wv[0]; wcr[4 * k4 + 1] = wv[1];
        wcr[4 * k4 + 2] = wv[2]; wcr[4 * k4 + 3] = wv[3];
        f4 tv = *(const f4*)&Wt[lane * 32 + k4 * 4];
        wtr[4 * k4] = tv[0]; wtr[4 * k4 + 1] = tv[1];
        wtr[4 * k4 + 2] = tv[2]; wtr[4 * k4 + 3] = tv[3];
    }
    const float bcj = bc[jm], btj = bt[lane];
#pragma unroll 1
    for (int row = gw; row < NB; row += 3072) {
        if (s[row] >= 4) continue;
        int tok = x[row * 16];
        const f4* ep = (const f4*)&emb[tok * 32];
        float a = bcj;
#pragma unroll
        for (int k4 = 0; k4 < 8; ++k4) {
            f4 ev = ep[k4];
            a = fmaf(ev[0], wcr[4 * k4], a);
            a = fmaf(ev[1], wcr[4 * k4 + 1], a);
            a = fmaf(ev[2], wcr[4 * k4 + 2], a);
            a = fmaf(ev[3], wcr[4 * k4 + 3], a);
        }
        float comb = fmaxf(a, 0.f);
        float logit = btj;
#pragma unroll
        for (int k = 0; k < 32; ++k) logit = fmaf(__shfl(comb, k), wtr[k], logit);
        float mx = logit;
#pragma unroll
        for (int off = 32; off; off >>= 1) mx = fmaxf(mx, __shfl_xor(mx, off));
        float ex = __expf(logit - mx), sm = ex;
#pragma unroll
        for (int off = 32; off; off >>= 1) sm += __shfl_xor(sm, off);
        out[row * 64 + lane] = logit - mx - __logf(sm);
    }
}

// ---------------- fallback (small ws): round-2 monolithic fp32 kernel ----------------
__global__ __launch_bounds__(512) void tagger_fallback(
    const int* __restrict__ x, const int* __restrict__ s, const float* __restrict__ emb,
    const float* __restrict__ Wih, const float* __restrict__ Whh,
    const float* __restrict__ bih, const float* __restrict__ bhh,
    const float* __restrict__ h0, const float* __restrict__ c0,
    const float* __restrict__ Wc, const float* __restrict__ bc,
    const float* __restrict__ Wt, const float* __restrict__ bt,
    float* __restrict__ out) {
    __shared__ float4 WhhP[4096];
    __shared__ float combBuf[8][128];
    for (int i = threadIdx.x; i < 4096; i += 512) {
        int k = i & 63, jj = i >> 6;
        WhhP[k * 64 + jj] = make_float4(Whh[jj * 64 + k], Whh[(jj + 64) * 64 + k],
                                        Whh[(jj + 128) * 64 + k], Whh[(jj + 192) * 64 + k]);
    }
    __syncthreads();
    const int wave = threadIdx.x >> 6, j = threadIdx.x & 63, jm = j & 31;
    const int b = blockIdx.x * 8 + wave;
    const int sv = s[b];
    const int* xb = x + b * NT;
    const float bcj = bc[jm];
    auto rc_val = [&](int tok) -> float {
        float r = 0.f;
#pragma unroll
        for (int k = 0; k < 32; ++k) r = fmaf(emb[tok * NE + k], Wc[jm * 96 + k], r);
        return r;
    };
    float comb4;
    if (sv >= 4) {
        const float h0j = h0[j], c0j = c0[j];
        float4 bsj = make_float4(bih[j] + bhh[j], bih[j + 64] + bhh[j + 64],
                                 bih[j + 128] + bhh[j + 128], bih[j + 192] + bhh[j + 192]);
#pragma unroll 1
        for (int node = 0; node < 4; ++node) {
            float h = h0j, c = c0j;
#pragma unroll 1
            for (int t = 0; t < 4; ++t) {
                int tok = xb[node * 4 + t];
                float4 p = bsj;
#pragma unroll
                for (int k = 0; k < 32; ++k) {
                    float e = emb[tok * NE + k];
                    p.x = fmaf(e, Wih[j * 32 + k], p.x);
                    p.y = fmaf(e, Wih[(j + 64) * 32 + k], p.y);
                    p.z = fmaf(e, Wih[(j + 128) * 32 + k], p.z);
                    p.w = fmaf(e, Wih[(j + 192) * 32 + k], p.w);
                }
                float4 a = make_float4(0.f, 0.f, 0.f, 0.f);
#pragma unroll
                for (int k = 0; k < 64; ++k) {
                    float hk = __shfl(h, k);
                    float4 w = WhhP[k * 64 + j];
                    a.x = fmaf(hk, w.x, a.x); a.y = fmaf(hk, w.y, a.y);
                    a.z = fmaf(hk, w.z, a.z); a.w = fmaf(hk, w.w, a.w);
                }
                a.x += p.x; a.y += p.y; a.z += p.z; a.w += p.w;
                float ig = sigm_(a.x), fg = sigm_(a.y), gg = tanh_(a.z), og = sigm_(a.w);
                c = fmaf(fg, c, ig * gg);
                h = og * tanh_(c);
            }
            float last = fmaxf(h, 0.f);
            float acc = rc_val(xb[node * 4]) + bcj;
#pragma unroll
            for (int k = 0; k < 64; ++k)
                acc = fmaf(__shfl(last, k), Wc[jm * 96 + 32 + k], acc);
            if (j < 32) combBuf[wave][node * 32 + j] = fmaxf(acc, 0.f);
        }
        LDSSYNC();
        float h = h0j, c = c0j;
#pragma unroll 1
        for (int t = 0; t < 4; ++t) {
            float4 a = make_float4(0.f, 0.f, 0.f, 0.f);
#pragma unroll
            for (int k = 0; k < 32; ++k) {
                float ck = combBuf[wave][t * 32 + k];
                a.x = fmaf(ck, Wih[j * 32 + k], a.x);
                a.y = fmaf(ck, Wih[(j + 64) * 32 + k], a.y);
                a.z = fmaf(ck, Wih[(j + 128) * 32 + k], a.z);
                a.w = fmaf(ck, Wih[(j + 192) * 32 + k], a.w);
            }
#pragma unroll
            for (int k = 0; k < 64; ++k) {
                float hk = __shfl(h, k);
                float4 w = WhhP[k * 64 + j];
                a.x = fmaf(hk, w.x, a.x); a.y = fmaf(hk, w.y, a.y);
                a.z = fmaf(hk, w.z, a.z); a.w = fmaf(hk, w.w, a.w);
            }
            a.x += bih[j] + bhh[j]; a.y += bih[j + 64] + bhh[j + 64];
            a.z += bih[j + 128] + bhh[j + 128]; a.w += bih[j + 192] + bhh[j + 192];
            float ig = sigm_(a.x), fg = sigm_(a.y), gg = tanh_(a.z), og = sigm_(a.w);
            c = fmaf(fg, c, ig * gg);
            h = og * tanh_(c);
        }
        float last = fmaxf(h, 0.f);
        float acc = rc_val(xb[0]) + bcj;
#pragma unroll
        for (int k = 0; k < 64; ++k)
            acc = fmaf(__shfl(last, k), Wc[jm * 96 + 32 + k], acc);
        comb4 = fmaxf(acc, 0.f);
    } else {
        comb4 = fmaxf(rc_val(xb[0]) + bcj, 0.f);
    }
    float logit = bt[j];
    const float* wtr = Wt + j * 32;
#pragma unroll
    for (int k = 0; k < 32; ++k) logit = fmaf(__shfl(comb4, k), wtr[k], logit);
    float mx = logit;
#pragma unroll
    for (int off = 32; off; off >>= 1) mx = fmaxf(mx, __shfl_xor(mx, off));
    float ex = __expf(logit - mx);
    float sum = ex;
#pragma unroll
    for (int off = 32; off; off >>= 1) sum += __shfl_xor(sum, off);
    out[b * 64 + j] = logit - mx - __logf(sum);
}

extern "C" void kernel_launch(void* const* d_in, const int* in_sizes, int n_in,
                              void* d_out, int out_size, void* d_ws, size_t ws_size,
                              hipStream_t stream) {
    const int* x = (const int*)d_in[0];
    const int* s = (const int*)d_in[1];
    const float* emb = (const float*)d_in[2];
    const float* Wih = (const float*)d_in[3];
    const float* Whh = (const float*)d_in[4];
    const float* bih = (const float*)d_in[5];
    const float* bhh = (const float*)d_in[6];
    const float* h0 = (const float*)d_in[7];
    const float* c0 = (const float*)d_in[8];
    const float* Wc = (const float*)d_in[9];
    const float* bc = (const float*)d_in[10];
    const float* Wt = (const float*)d_in[11];
    const float* bt = (const float*)d_in[12];
    float* out = (float*)d_out;

    auto al16 = [](size_t v) { return (v + 15) & ~(size_t)15; };
    size_t off = 0;
    size_t oWpack = off; off = al16(off + (size_t)28672 * 2);       // WhhHi+WihHi
    size_t oWc1 = off;   off = al16(off + 1024 * 2);
    size_t oWc2 = off;   off = al16(off + 2048 * 2);
    size_t oWt = off;    off = al16(off + 2048 * 2);
    size_t oBsum = off;  off = al16(off + 256 * 4);
    size_t oEmbH = off;  off = al16(off + (size_t)NV * NE * 2);
    size_t oCnt = off;   off = al16(off + 16);
    size_t oList = off;  off = al16(off + (size_t)NB * 4);
    size_t need = off;

    char* ws = (char*)d_ws;
    if (ws_size >= need) {
        short* wpack = (short*)(ws + oWpack);
        short* wc1 = (short*)(ws + oWc1);
        short* wc2 = (short*)(ws + oWc2);
        short* wth = (short*)(ws + oWt);
        float* bsum = (float*)(ws + oBsum);
        short* embH = (short*)(ws + oEmbH);
        int* cnt = (int*)(ws + oCnt);
        int* list = (int*)(ws + oList);

        hipMemsetAsync(cnt, 0, sizeof(int), stream);
        prep<<<dim3(4073), dim3(256), 0, stream>>>(emb, Wih, Whh, bih, bhh, Wc, Wt,
                                                   embH, wpack, wc1, wc2, wth, bsum);
        classify_list<<<dim3(32), dim3(1024), 0, stream>>>(s, cnt, list);
        main_fused<<<dim3(768), dim3(256), 0, stream>>>(
            x, s, emb, h0, c0, Wc, bc, Wt, bt, bsum,
            wpack, wc1, wc2, wth, embH, cnt, list, out);
    } else {
        tagger_fallback<<<dim3(4096), dim3(512), 0, stream>>>(
            x, s, emb, Wih, Whh, bih, bhh, h0, c0, Wc, bc, Wt, bt, out);
    }
}

// Round 5
// 180.213 us; speedup vs baseline: 30.6080x; 1.1642x over previous
//
#include <hip/hip_runtime.h>

// Problem constants
#define NB 32768
#define NT 16
#define NV 32001   // V+1
#define NE 32
#define NTAGS 64

typedef __attribute__((ext_vector_type(8))) short short8;   // 8 bf16 (4 VGPR)
typedef __attribute__((ext_vector_type(4))) float f4;       // MFMA acc

#define MFMA16(a, b, c) __builtin_amdgcn_mfma_f32_16x16x32_bf16(a, b, c, 0, 0, 0)
// DS ops are in-order within a wave -> compiler-only fence suffices for same-wave LDS RAW
#define CFENCE() asm volatile("" ::: "memory")
#define LDSSYNC() asm volatile("s_waitcnt lgkmcnt(0)" ::: "memory")

__device__ __forceinline__ float sigm_(float x) {
    return __builtin_amdgcn_rcpf(1.0f + __expf(-x));
}
__device__ __forceinline__ float tanh2_(float x) {  // 2*sigm(2x)-1, no clamp needed
    float e = __expf(-2.0f * x);
    return fmaf(2.0f, __builtin_amdgcn_rcpf(1.0f + e), -1.0f);
}
__device__ __forceinline__ short f2bf(float x) {  // RNE float->bf16 bits
    union { float f; unsigned u; } v; v.f = x;
    unsigned r = v.u + 0x7fffu + ((v.u >> 16) & 1u);
    return (short)(r >> 16);
}

// ---------------- K1: classify (no atomics) + emb->bf16 + weight pack ----------------
// wpack: [WhhHi 256x72][WihHi 256x40]; wc1[32][32]; wc2[32][64]; wth[64][32]; bsum[256] f32
// cH[32] per-slab heavy counts; listH/listL slab-local compacted row lists.
__global__ __launch_bounds__(1024) void classify_prep(
    const int* __restrict__ s, const float* __restrict__ emb,
    const float* __restrict__ Wih, const float* __restrict__ Whh,
    const float* __restrict__ bih, const float* __restrict__ bhh,
    const float* __restrict__ Wc, const float* __restrict__ Wt,
    short* __restrict__ embH, short* __restrict__ wpack, short* __restrict__ wc1,
    short* __restrict__ wc2, short* __restrict__ wth, float* __restrict__ bsum,
    int* __restrict__ cH, int* __restrict__ listH, int* __restrict__ listL) {
    __shared__ int wbH[16], wbL[16];
    const int tid = threadIdx.x, b = blockIdx.x;
    const int row = b * 1024 + tid;
    const bool heavy = s[row] >= 4;
    unsigned long long mk = __ballot(heavy);
    const int wv = tid >> 6, ln = tid & 63;
    if (ln == 0) wbH[wv] = __popcll(mk);
    __syncthreads();
    if (tid == 0) {
        int tH = 0, tL = 0;
#pragma unroll
        for (int i = 0; i < 16; ++i) {
            int ch = wbH[i];
            wbH[i] = tH; wbL[i] = tL;
            tH += ch; tL += 64 - ch;
        }
        cH[b] = tH;
    }
    __syncthreads();
    unsigned long long ltm = (1ull << ln) - 1ull;
    if (heavy) listH[b * 1024 + wbH[wv] + __popcll(mk & ltm)] = row;
    else       listL[b * 1024 + wbL[wv] + __popcll((~mk) & ltm)] = row;
    // emb -> bf16 (stripe across 32 blocks)
    for (int i = b * 1024 + tid; i < NV * NE; i += 32768) embH[i] = f2bf(emb[i]);
    if (b == 0) {
        for (int t = tid; t < 18432; t += 1024) {
            int r = t / 72, c = t % 72;
            wpack[t] = f2bf(c < 64 ? Whh[r * 64 + c] : 0.f);
        }
        for (int t = tid; t < 10240; t += 1024) {
            int r = t / 40, c = t % 40;
            wpack[18432 + t] = f2bf(c < 32 ? Wih[r * 32 + c] : 0.f);
        }
        if (tid < 1024) { int r = tid >> 5, c = tid & 31; wc1[tid] = f2bf(Wc[r * 96 + c]); }
        for (int t = tid; t < 2048; t += 1024) {
            int r = t >> 6, c = t & 63;
            wc2[t] = f2bf(Wc[r * 96 + 32 + c]);
        }
        for (int t = tid; t < 2048; t += 1024) {
            int r = t >> 5, c = t & 31;
            wth[t] = f2bf(Wt[r * 32 + c]);
        }
        if (tid < 256) bsum[tid] = bih[tid] + bhh[tid];
    }
}

// ---------------- K2: fused main — heavy (16 rows/wave, MFMA) + light ----------------
__global__ __launch_bounds__(256, 2) void main_fused(
    const int* __restrict__ x, const float* __restrict__ emb,
    const float* __restrict__ h0, const float* __restrict__ c0,
    const float* __restrict__ Wc, const float* __restrict__ bc,
    const float* __restrict__ Wt, const float* __restrict__ bt,
    const float* __restrict__ bsum,
    const short* __restrict__ wpack, const short* __restrict__ wc1,
    const short* __restrict__ wc2, const short* __restrict__ wth,
    const short* __restrict__ embH, const int* __restrict__ cH,
    const int* __restrict__ listH, const int* __restrict__ listL,
    float* __restrict__ out) {
    __shared__ __align__(16) short sWhh[18432];        // 36 KB [256][72]
    __shared__ __align__(16) short sHA[4][16 * 72];    // per-wave h, A-frag layout (bf16)
    __shared__ __align__(16) short sCmb[4][16 * 168];  // per-wave comb[row][node*40+col]
    __shared__ __align__(16) short sC4[4][16 * 40];    // per-wave comb4[row][col]

    const int tid = threadIdx.x, wave = tid >> 6, lane = tid & 63;
    const int q = lane >> 4, n = lane & 15;
    const int NW = gridDim.x * 4;
    const int gw = blockIdx.x * 4 + wave;

    // 32-slab prefix scan (per wave, shfl)
    int cs = (lane < 32) ? cH[lane] : 0;
    int v = cs;
#pragma unroll
    for (int o = 1; o < 32; o <<= 1) { int t2 = __shfl_up(v, o); if (lane >= o) v += t2; }
    const int vIncl = v, vExcl = v - cs;
    const int nH = __shfl(vIncl, 31);
    const int nL = NB - nH;
    const int nHWaves = (nH + 15) >> 4;
    const int liIncl = (lane + 1) * 1024 - vIncl;  // light prefixes (lane<32)
    const int liExcl = lane * 1024 - vExcl;

    const bool blkHeavy = (int)blockIdx.x * 4 < nHWaves;
    if (blkHeavy) {
        for (int i = tid; i < 1152; i += 256)
            ((uint4*)sWhh)[i] = ((const uint4*)wpack)[i];
        __syncthreads();
    }

    if (gw < nHWaves) {
        short* hA = sHA[wave];
        short* cmb = sCmb[wave];
        short* c4 = sC4[wave];
        const short* wihG = wpack + 18432;  // [256][40] bf16, L1-hot

        // bias splats as MFMA C operands
        f4 biasV[16];
#pragma unroll
        for (int tl = 0; tl < 16; ++tl) { float bv = bsum[tl * 16 + n]; biasV[tl] = f4{bv, bv, bv, bv}; }
        f4 bcV[2];
#pragma unroll
        for (int t = 0; t < 2; ++t) { float bv = bc[t * 16 + n]; bcV[t] = f4{bv, bv, bv, bv}; }
        f4 btV[4];
#pragma unroll
        for (int t = 0; t < 4; ++t) { float bv = bt[t * 16 + n]; btV[t] = f4{bv, bv, bv, bv}; }
        float c0v[4]; short h0b[4];
#pragma unroll
        for (int u = 0; u < 4; ++u) { c0v[u] = c0[u * 16 + n]; h0b[u] = f2bf(h0[u * 16 + n]); }

        f4 acc[16];
        float cst[4][4];

        auto initSt = [&]() {
#pragma unroll
            for (int u = 0; u < 4; ++u) {
                short hb = h0b[u];
#pragma unroll
                for (int r = 0; r < 4; ++r) {
                    cst[r][u] = c0v[u];
                    hA[(q * 4 + r) * 72 + u * 16 + n] = hb;
                }
            }
            CFENCE();
        };
        auto doStep = [&](short8 aP, bool doRelu) {
            short8 ah0 = *(const short8*)&hA[n * 72 + q * 8];
            short8 ah1 = *(const short8*)&hA[n * 72 + 32 + q * 8];
#pragma unroll
            for (int tl = 0; tl < 16; ++tl) {
                short8 bW = *(const short8*)&wihG[(tl * 16 + n) * 40 + q * 8];
                acc[tl] = MFMA16(aP, bW, biasV[tl]);
            }
#pragma unroll
            for (int tl = 0; tl < 16; ++tl) {
                const short* rbp = &sWhh[(tl * 16 + n) * 72 + q * 8];
                f4 t0 = acc[tl];
                t0 = MFMA16(ah0, *(const short8*)rbp, t0);
                t0 = MFMA16(ah1, *(const short8*)(rbp + 32), t0);
                acc[tl] = t0;
            }
            CFENCE();
#pragma unroll
            for (int u = 0; u < 4; ++u)
#pragma unroll
                for (int r = 0; r < 4; ++r) {
                    float ip = acc[u][r], fp = acc[4 + u][r];
                    float gp = acc[8 + u][r], op = acc[12 + u][r];
                    float cc = fmaf(sigm_(fp), cst[r][u], sigm_(ip) * tanh2_(gp));
                    cst[r][u] = cc;
                    float hh = sigm_(op) * tanh2_(cc);
                    if (doRelu) hh = fmaxf(hh, 0.f);
                    hA[(q * 4 + r) * 72 + u * 16 + n] = f2bf(hh);
                }
            CFENCE();
        };

#pragma unroll 1
        for (int it = gw; it * 16 < nH; it += NW) {
            const int base = it * 16;
            // rows for this iteration (lane i<16 holds row of idx base+i)
            int idx = min(base + lane, nH - 1);
            int sl = 0;
#pragma unroll
            for (int b2 = 0; b2 < 32; ++b2) sl += (__shfl(vIncl, b2) <= idx) ? 1 : 0;
            const int rowv = listH[sl * 1024 + idx - __shfl(vExcl, sl)];
            const int myrow = __shfl(rowv, lane >> 2);
            const int4 x4 = *(const int4*)&x[myrow * 16 + (lane & 3) * 4];

            // ---- phase 1: 4 groups of (4 rows x 4 nodes) ----
#pragma unroll 1
            for (int g = 0; g < 4; ++g) {
                initSt();
                const int Lt = 16 * g + 4 * (n & 3) + (n >> 2);
                int tok = __shfl(x4.x, Lt);
                short8 aNext = *(const short8*)&embH[tok * 32 + q * 8];
                const short8 aRoot = aNext;
#pragma unroll 1
                for (int t = 0; t < 4; ++t) {
                    short8 aP = aNext;
                    if (t < 3) {
                        int xc = (t == 0) ? x4.y : (t == 1) ? x4.z : x4.w;
                        int tk2 = __shfl(xc, Lt);
                        aNext = *(const short8*)&embH[tk2 * 32 + q * 8];
                    }
                    doStep(aP, t == 3);
                }
                // comb for group g: unit q*4+r -> (row_local 4g+r, node q)
                {
                    short8 lh0 = *(const short8*)&hA[n * 72 + q * 8];
                    short8 lh1 = *(const short8*)&hA[n * 72 + 32 + q * 8];
#pragma unroll
                    for (int tl2 = 0; tl2 < 2; ++tl2) {
                        f4 t0 = bcV[tl2];
                        short8 b1 = *(const short8*)&wc1[(tl2 * 16 + n) * 32 + q * 8];
                        t0 = MFMA16(aRoot, b1, t0);
                        const short* rbp = &wc2[(tl2 * 16 + n) * 64 + q * 8];
                        t0 = MFMA16(lh0, *(const short8*)rbp, t0);
                        t0 = MFMA16(lh1, *(const short8*)(rbp + 32), t0);
#pragma unroll
                        for (int r = 0; r < 4; ++r)
                            cmb[(4 * g + r) * 168 + q * 40 + tl2 * 16 + n] =
                                f2bf(fmaxf(t0[r], 0.f));
                    }
                    CFENCE();
                }
            }

            // ---- phase 2: node 4 for all 16 rows (children = comb_0..3) ----
            initSt();
            int tokR = __shfl(x4.x, 4 * n);
            short8 aR4 = *(const short8*)&embH[tokR * 32 + q * 8];
#pragma unroll 1
            for (int t = 0; t < 4; ++t) {
                short8 aC = *(const short8*)&cmb[n * 168 + t * 40 + q * 8];
                doStep(aC, t == 3);
            }
            {   // comb4: unit = row q*4+r
                short8 lh0 = *(const short8*)&hA[n * 72 + q * 8];
                short8 lh1 = *(const short8*)&hA[n * 72 + 32 + q * 8];
#pragma unroll
                for (int tl2 = 0; tl2 < 2; ++tl2) {
                    f4 t0 = bcV[tl2];
                    short8 b1 = *(const short8*)&wc1[(tl2 * 16 + n) * 32 + q * 8];
                    t0 = MFMA16(aR4, b1, t0);
                    const short* rbp = &wc2[(tl2 * 16 + n) * 64 + q * 8];
                    t0 = MFMA16(lh0, *(const short8*)rbp, t0);
                    t0 = MFMA16(lh1, *(const short8*)(rbp + 32), t0);
#pragma unroll
                    for (int r = 0; r < 4; ++r)
                        c4[(q * 4 + r) * 40 + tl2 * 16 + n] = f2bf(fmaxf(t0[r], 0.f));
                }
                CFENCE();
            }

            // ---- phase 3: logits + log_softmax for 16 rows ----
            {
                short8 cA = *(const short8*)&c4[n * 40 + q * 8];
                f4 a3[4];
#pragma unroll
                for (int tl3 = 0; tl3 < 4; ++tl3) {
                    short8 bW = *(const short8*)&wth[(tl3 * 16 + n) * 32 + q * 8];
                    a3[tl3] = MFMA16(cA, bW, btV[tl3]);
                }
#pragma unroll
                for (int r = 0; r < 4; ++r) {
                    float l0 = a3[0][r], l1 = a3[1][r], l2 = a3[2][r], l3 = a3[3][r];
                    float mx = fmaxf(fmaxf(l0, l1), fmaxf(l2, l3));
#pragma unroll
                    for (int o2 = 8; o2; o2 >>= 1) mx = fmaxf(mx, __shfl_xor(mx, o2));
                    float sm = __expf(l0 - mx) + __expf(l1 - mx) +
                               __expf(l2 - mx) + __expf(l3 - mx);
#pragma unroll
                    for (int o2 = 8; o2; o2 >>= 1) sm += __shfl_xor(sm, o2);
                    float lse = mx + __logf(sm);
                    int rowO = __shfl(rowv, q * 4 + r);
                    if (base + q * 4 + r < nH) {
                        out[rowO * 64 + n] = l0 - lse;
                        out[rowO * 64 + 16 + n] = l1 - lse;
                        out[rowO * 64 + 32 + n] = l2 - lse;
                        out[rowO * 64 + 48 + n] = l3 - lse;
                    }
                }
            }
        }
    }

    // ---- light rows: out depends only on x[row][0] ----
    const int lStart = (nHWaves < NW) ? nHWaves : 0;
    const int lStride = NW - lStart;
    if (gw >= lStart && nL > 0) {
        const int jm = lane & 31;
        float wcr[32], wtr[32];
#pragma unroll
        for (int k4 = 0; k4 < 8; ++k4) {
            f4 wv2 = *(const f4*)&Wc[jm * 96 + k4 * 4];
            wcr[4 * k4] = wv2[0]; wcr[4 * k4 + 1] = wv2[1];
            wcr[4 * k4 + 2] = wv2[2]; wcr[4 * k4 + 3] = wv2[3];
            f4 tv = *(const f4*)&Wt[lane * 32 + k4 * 4];
            wtr[4 * k4] = tv[0]; wtr[4 * k4 + 1] = tv[1];
            wtr[4 * k4 + 2] = tv[2]; wtr[4 * k4 + 3] = tv[3];
        }
        const float bcj = bc[jm], btj = bt[lane];
        auto lookupL = [&](int i) {
            unsigned long long m = __ballot((lane < 32) && (liIncl <= i));
            int slab = __popcll(m);
            return listL[slab * 1024 + i - __shfl(liExcl, slab)];
        };
        int i = gw - lStart;
        int row = 0, tok = 0;
        if (i < nL) { row = lookupL(i); tok = x[row * 16]; }
#pragma unroll 1
        while (i < nL) {
            int inext = i + lStride;
            int rowN = 0, tokN = 0;
            bool hasN = inext < nL;
            if (hasN) { rowN = lookupL(inext); tokN = x[rowN * 16]; }  // in flight
            const f4* ep = (const f4*)&emb[tok * 32];
            float a = bcj;
#pragma unroll
            for (int k4 = 0; k4 < 8; ++k4) {
                f4 ev = ep[k4];
                a = fmaf(ev[0], wcr[4 * k4], a);
                a = fmaf(ev[1], wcr[4 * k4 + 1], a);
                a = fmaf(ev[2], wcr[4 * k4 + 2], a);
                a = fmaf(ev[3], wcr[4 * k4 + 3], a);
            }
            float comb = fmaxf(a, 0.f);
            float logit = btj;
#pragma unroll
            for (int k = 0; k < 32; ++k) logit = fmaf(__shfl(comb, k), wtr[k], logit);
            float mx = logit;
#pragma unroll
            for (int o2 = 32; o2; o2 >>= 1) mx = fmaxf(mx, __shfl_xor(mx, o2));
            float ex = __expf(logit - mx), sm = ex;
#pragma unroll
            for (int o2 = 32; o2; o2 >>= 1) sm += __shfl_xor(sm, o2);
            out[row * 64 + lane] = logit - mx - __logf(sm);
            row = rowN; tok = tokN; i = inext;
        }
    }
}

// ---------------- fallback (small ws): monolithic fp32 kernel ----------------
__global__ __launch_bounds__(512) void tagger_fallback(
    const int* __restrict__ x, const int* __restrict__ s, const float* __restrict__ emb,
    const float* __restrict__ Wih, const float* __restrict__ Whh,
    const float* __restrict__ bih, const float* __restrict__ bhh,
    const float* __restrict__ h0, const float* __restrict__ c0,
    const float* __restrict__ Wc, const float* __restrict__ bc,
    const float* __restrict__ Wt, const float* __restrict__ bt,
    float* __restrict__ out) {
    __shared__ float4 WhhP[4096];
    __shared__ float combBuf[8][128];
    for (int i = threadIdx.x; i < 4096; i += 512) {
        int k = i & 63, jj = i >> 6;
        WhhP[k * 64 + jj] = make_float4(Whh[jj * 64 + k], Whh[(jj + 64) * 64 + k],
                                        Whh[(jj + 128) * 64 + k], Whh[(jj + 192) * 64 + k]);
    }
    __syncthreads();
    const int wave = threadIdx.x >> 6, j = threadIdx.x & 63, jm = j & 31;
    const int b = blockIdx.x * 8 + wave;
    const int sv = s[b];
    const int* xb = x + b * NT;
    const float bcj = bc[jm];
    auto rc_val = [&](int tok) -> float {
        float r = 0.f;
#pragma unroll
        for (int k = 0; k < 32; ++k) r = fmaf(emb[tok * NE + k], Wc[jm * 96 + k], r);
        return r;
    };
    float comb4;
    if (sv >= 4) {
        const float h0j = h0[j], c0j = c0[j];
        float4 bsj = make_float4(bih[j] + bhh[j], bih[j + 64] + bhh[j + 64],
                                 bih[j + 128] + bhh[j + 128], bih[j + 192] + bhh[j + 192]);
#pragma unroll 1
        for (int node = 0; node < 4; ++node) {
            float h = h0j, c = c0j;
#pragma unroll 1
            for (int t = 0; t < 4; ++t) {
                int tok = xb[node * 4 + t];
                float4 p = bsj;
#pragma unroll
                for (int k = 0; k < 32; ++k) {
                    float e = emb[tok * NE + k];
                    p.x = fmaf(e, Wih[j * 32 + k], p.x);
                    p.y = fmaf(e, Wih[(j + 64) * 32 + k], p.y);
                    p.z = fmaf(e, Wih[(j + 128) * 32 + k], p.z);
                    p.w = fmaf(e, Wih[(j + 192) * 32 + k], p.w);
                }
                float4 a = make_float4(0.f, 0.f, 0.f, 0.f);
#pragma unroll
                for (int k = 0; k < 64; ++k) {
                    float hk = __shfl(h, k);
                    float4 w = WhhP[k * 64 + j];
                    a.x = fmaf(hk, w.x, a.x); a.y = fmaf(hk, w.y, a.y);
                    a.z = fmaf(hk, w.z, a.z); a.w = fmaf(hk, w.w, a.w);
                }
                a.x += p.x; a.y += p.y; a.z += p.z; a.w += p.w;
                float ig = sigm_(a.x), fg = sigm_(a.y), gg = tanh2_(a.z), og = sigm_(a.w);
                c = fmaf(fg, c, ig * gg);
                h = og * tanh2_(c);
            }
            float last = fmaxf(h, 0.f);
            float acc = rc_val(xb[node * 4]) + bcj;
#pragma unroll
            for (int k = 0; k < 64; ++k)
                acc = fmaf(__shfl(last, k), Wc[jm * 96 + 32 + k], acc);
            if (j < 32) combBuf[wave][node * 32 + j] = fmaxf(acc, 0.f);
        }
        LDSSYNC();
        float h = h0j, c = c0j;
#pragma unroll 1
        for (int t = 0; t < 4; ++t) {
            float4 a = make_float4(0.f, 0.f, 0.f, 0.f);
#pragma unroll
            for (int k = 0; k < 32; ++k) {
                float ck = combBuf[wave][t * 32 + k];
                a.x = fmaf(ck, Wih[j * 32 + k], a.x);
                a.y = fmaf(ck, Wih[(j + 64) * 32 + k], a.y);
                a.z = fmaf(ck, Wih[(j + 128) * 32 + k], a.z);
                a.w = fmaf(ck, Wih[(j + 192) * 32 + k], a.w);
            }
#pragma unroll
            for (int k = 0; k < 64; ++k) {
                float hk = __shfl(h, k);
                float4 w = WhhP[k * 64 + j];
                a.x = fmaf(hk, w.x, a.x); a.y = fmaf(hk, w.y, a.y);
                a.z = fmaf(hk, w.z, a.z); a.w = fmaf(hk, w.w, a.w);
            }
            a.x += bih[j] + bhh[j]; a.y += bih[j + 64] + bhh[j + 64];
            a.z += bih[j + 128] + bhh[j + 128]; a.w += bih[j + 192] + bhh[j + 192];
            float ig = sigm_(a.x), fg = sigm_(a.y), gg = tanh2_(a.z), og = sigm_(a.w);
            c = fmaf(fg, c, ig * gg);
            h = og * tanh2_(c);
        }
        float last = fmaxf(h, 0.f);
        float acc = rc_val(xb[0]) + bcj;
#pragma unroll
        for (int k = 0; k < 64; ++k)
            acc = fmaf(__shfl(last, k), Wc[jm * 96 + 32 + k], acc);
        comb4 = fmaxf(acc, 0.f);
    } else {
        comb4 = fmaxf(rc_val(xb[0]) + bcj, 0.f);
    }
    float logit = bt[j];
    const float* wtr = Wt + j * 32;
#pragma unroll
    for (int k = 0; k < 32; ++k) logit = fmaf(__shfl(comb4, k), wtr[k], logit);
    float mx = logit;
#pragma unroll
    for (int off = 32; off; off >>= 1) mx = fmaxf(mx, __shfl_xor(mx, off));
    float ex = __expf(logit - mx);
    float sum = ex;
#pragma unroll
    for (int off = 32; off; off >>= 1) sum += __shfl_xor(sum, off);
    out[b * 64 + j] = logit - mx - __logf(sum);
}

extern "C" void kernel_launch(void* const* d_in, const int* in_sizes, int n_in,
                              void* d_out, int out_size, void* d_ws, size_t ws_size,
                              hipStream_t stream) {
    const int* x = (const int*)d_in[0];
    const int* s = (const int*)d_in[1];
    const float* emb = (const float*)d_in[2];
    const float* Wih = (const float*)d_in[3];
    const float* Whh = (const float*)d_in[4];
    const float* bih = (const float*)d_in[5];
    const float* bhh = (const float*)d_in[6];
    const float* h0 = (const float*)d_in[7];
    const float* c0 = (const float*)d_in[8];
    const float* Wc = (const float*)d_in[9];
    const float* bc = (const float*)d_in[10];
    const float* Wt = (const float*)d_in[11];
    const float* bt = (const float*)d_in[12];
    float* out = (float*)d_out;

    auto al16 = [](size_t v) { return (v + 15) & ~(size_t)15; };
    size_t off = 0;
    size_t oWpack = off; off = al16(off + (size_t)28672 * 2);  // WhhHi[256x72]+WihHi[256x40]
    size_t oWc1 = off;   off = al16(off + 1024 * 2);
    size_t oWc2 = off;   off = al16(off + 2048 * 2);
    size_t oWt = off;    off = al16(off + 2048 * 2);
    size_t oBsum = off;  off = al16(off + 256 * 4);
    size_t oEmbH = off;  off = al16(off + (size_t)NV * NE * 2);
    size_t oCH = off;    off = al16(off + 32 * 4);
    size_t oListH = off; off = al16(off + (size_t)NB * 4);
    size_t oListL = off; off = al16(off + (size_t)NB * 4);
    size_t need = off;

    char* ws = (char*)d_ws;
    if (ws_size >= need) {
        short* wpack = (short*)(ws + oWpack);
        short* wc1 = (short*)(ws + oWc1);
        short* wc2 = (short*)(ws + oWc2);
        short* wth = (short*)(ws + oWt);
        float* bsum = (float*)(ws + oBsum);
        short* embH = (short*)(ws + oEmbH);
        int* cHp = (int*)(ws + oCH);
        int* listH = (int*)(ws + oListH);
        int* listL = (int*)(ws + oListL);

        classify_prep<<<dim3(32), dim3(1024), 0, stream>>>(
            s, emb, Wih, Whh, bih, bhh, Wc, Wt,
            embH, wpack, wc1, wc2, wth, bsum, cHp, listH, listL);
        main_fused<<<dim3(512), dim3(256), 0, stream>>>(
            x, emb, h0, c0, Wc, bc, Wt, bt, bsum,
            wpack, wc1, wc2, wth, embH, cHp, listH, listL, out);
    } else {
        tagger_fallback<<<dim3(4096), dim3(512), 0, stream>>>(
            x, s, emb, Wih, Whh, bih, bhh, h0, c0, Wc, bc, Wt, bt, out);
    }
}

// Round 7
// 166.440 us; speedup vs baseline: 33.1408x; 1.0827x over previous
//
#include <hip/hip_runtime.h>

// Problem constants
#define NB 32768
#define NT 16
#define NV 32001   // V+1
#define NE 32
#define NTAGS 64

typedef __attribute__((ext_vector_type(8))) short short8;   // 8 bf16 (4 VGPR)
typedef __attribute__((ext_vector_type(4))) float f4;       // MFMA acc

#define MFMA16(a, b, c) __builtin_amdgcn_mfma_f32_16x16x32_bf16(a, b, c, 0, 0, 0)
// DS ops are in-order within a wave -> compiler-only fence suffices for same-wave LDS RAW
#define CFENCE() asm volatile("" ::: "memory")
#define LDSSYNC() asm volatile("s_waitcnt lgkmcnt(0)" ::: "memory")

__device__ __forceinline__ float sigm_(float x) {
    return __builtin_amdgcn_rcpf(1.0f + __expf(-x));
}
__device__ __forceinline__ float tanh2_(float x) {  // 2*sigm(2x)-1
    float e = __expf(-2.0f * x);
    return fmaf(2.0f, __builtin_amdgcn_rcpf(1.0f + e), -1.0f);
}
__device__ __forceinline__ short f2bf(float x) {  // RNE float->bf16 bits
    union { float f; unsigned u; } v; v.f = x;
    unsigned r = v.u + 0x7fffu + ((v.u >> 16) & 1u);
    return (short)(r >> 16);
}

// ---------------- K1: classify (32 slabs, no atomics) + emb->bf16 + weight pack ----------------
__global__ __launch_bounds__(1024) void classify_prep(
    const int* __restrict__ s, const float* __restrict__ emb,
    const float* __restrict__ Wih, const float* __restrict__ Whh,
    const float* __restrict__ bih, const float* __restrict__ bhh,
    const float* __restrict__ Wc, const float* __restrict__ Wt,
    short* __restrict__ embH, short* __restrict__ wpack, short* __restrict__ wc1,
    short* __restrict__ wc2, short* __restrict__ wth, float* __restrict__ bsum,
    int* __restrict__ cH, int* __restrict__ listH, int* __restrict__ listL) {
    __shared__ int wbH[16], wbL[16];
    const int tid = threadIdx.x, b = blockIdx.x;
    if (b < 32) {
        const int row = b * 1024 + tid;
        const bool heavy = s[row] >= 4;
        unsigned long long mk = __ballot(heavy);
        const int wv = tid >> 6, ln = tid & 63;
        if (ln == 0) wbH[wv] = __popcll(mk);
        __syncthreads();
        if (tid == 0) {
            int tH = 0, tL = 0;
#pragma unroll
            for (int i = 0; i < 16; ++i) {
                int ch = wbH[i];
                wbH[i] = tH; wbL[i] = tL;
                tH += ch; tL += 64 - ch;
            }
            cH[b] = tH;
        }
        __syncthreads();
        unsigned long long ltm = (1ull << ln) - 1ull;
        if (heavy) listH[b * 1024 + wbH[wv] + __popcll(mk & ltm)] = row;
        else       listL[b * 1024 + wbL[wv] + __popcll((~mk) & ltm)] = row;
    }
    // emb -> bf16 (striped over all 256 blocks)
    for (int i = b * 1024 + tid; i < NV * NE; i += 262144) embH[i] = f2bf(emb[i]);
    if (b == 32) {  // weight pack
        for (int t = tid; t < 18432; t += 1024) {
            int r = t / 72, c = t % 72;
            wpack[t] = f2bf(c < 64 ? Whh[r * 64 + c] : 0.f);
        }
        for (int t = tid; t < 10240; t += 1024) {
            int r = t / 40, c = t % 40;
            wpack[18432 + t] = f2bf(c < 32 ? Wih[r * 32 + c] : 0.f);
        }
        if (tid < 1024) { int r = tid >> 5, c = tid & 31; wc1[tid] = f2bf(Wc[r * 96 + c]); }
        for (int t = tid; t < 2048; t += 1024) {
            int r = t >> 6, c = t & 63;
            wc2[t] = f2bf(Wc[r * 96 + 32 + c]);
        }
        for (int t = tid; t < 2048; t += 1024) {
            int r = t >> 5, c = t & 31;
            wth[t] = f2bf(Wt[r * 32 + c]);
        }
        if (tid < 256) bsum[tid] = bih[tid] + bhh[tid];
    }
}

// ---------------- K2: fused main — heavy (4 rows/wave, 8-step chain) + light ----------------
__global__ __launch_bounds__(256, 2) void main_fused(
    const int* __restrict__ x, const float* __restrict__ emb,
    const float* __restrict__ h0, const float* __restrict__ c0,
    const float* __restrict__ Wc, const float* __restrict__ bc,
    const float* __restrict__ Wt, const float* __restrict__ bt,
    const float* __restrict__ bsum,
    const short* __restrict__ wpack, const short* __restrict__ wc1,
    const short* __restrict__ wc2, const short* __restrict__ wth,
    const short* __restrict__ embH, const int* __restrict__ cH,
    const int* __restrict__ listH, const int* __restrict__ listL,
    float* __restrict__ out) {
    __shared__ __align__(16) short sWhh[18432];      // 36 KB [256][72] bf16
    __shared__ __align__(16) short sHA[4][16 * 72];  // per-wave h, A-frag layout (bf16)
    __shared__ __align__(16) short sCmb[4][16 * 40]; // per-wave comb[(node*4+row)][40]
    __shared__ __align__(16) short sC4[4][4 * 40];   // per-wave comb4[row][40]

    // FULL staging: 18432 shorts = 36864 B = 2304 uint4.
    // (Rounds 4-6 copied only 1152 = half; g/o-gate recurrent rows 128..255 read
    //  uninitialized LDS. Rounds 4/5 "passed" because uninit LDS ~= 0 -> silently
    //  dropped g/o recurrence, model error ~0.03 < threshold. Now fixed.)
    for (int i = threadIdx.x; i < 2304; i += 256)
        ((uint4*)sWhh)[i] = ((const uint4*)wpack)[i];
    __syncthreads();

    const int tid = threadIdx.x, wave = tid >> 6, lane = tid & 63;
    const int q = lane >> 4, n = lane & 15;
    const int NW = gridDim.x * 4;  // 2048
    const int gw = blockIdx.x * 4 + wave;

    // 32-slab prefix scan (per wave, shfl)
    int cs = (lane < 32) ? cH[lane] : 0;
    int v = cs;
#pragma unroll
    for (int o = 1; o < 32; o <<= 1) { int t2 = __shfl_up(v, o); if (lane >= o) v += t2; }
    const int vIncl = v, vExcl = v - cs;
    const int nH = __shfl(vIncl, 31);
    const int nL = NB - nH;
    const int liIncl = (lane + 1) * 1024 - vIncl;  // light prefixes (lane<32)
    const int liExcl = lane * 1024 - vExcl;

    if (gw * 4 < nH) {
        short* hA = sHA[wave];
        short* cmb = sCmb[wave];
        short* c4 = sC4[wave];
        const short* wihG = wpack + 18432;

        // loop-invariant Wih fragments in registers (64 VGPR) — no per-step global loads
        short8 wihR[16];
#pragma unroll
        for (int tl = 0; tl < 16; ++tl)
            wihR[tl] = *(const short8*)&wihG[(tl * 16 + n) * 40 + q * 8];

        float bias16[16];
#pragma unroll
        for (int tl = 0; tl < 16; ++tl) bias16[tl] = bsum[tl * 16 + n];
        float bc2[2] = {bc[n], bc[16 + n]};
        float bt4[4] = {bt[n], bt[16 + n], bt[32 + n], bt[48 + n]};
        float c0v[4]; short h0b[4];
#pragma unroll
        for (int u = 0; u < 4; ++u) { c0v[u] = c0[u * 16 + n]; h0b[u] = f2bf(h0[u * 16 + n]); }

        const f4 zero4 = {0.f, 0.f, 0.f, 0.f};
        f4 acc[16];
        float cst[4][4];

        auto initSt = [&]() {
#pragma unroll
            for (int u = 0; u < 4; ++u) {
                short hb = h0b[u];
#pragma unroll
                for (int r = 0; r < 4; ++r) {
                    cst[r][u] = c0v[u];
                    hA[(q * 4 + r) * 72 + u * 16 + n] = hb;
                }
            }
            CFENCE();
        };
        auto doStep = [&](short8 aP, bool doRelu) {
            short8 ah0 = *(const short8*)&hA[n * 72 + q * 8];
            short8 ah1 = *(const short8*)&hA[n * 72 + 32 + q * 8];
#pragma unroll
            for (int tl = 0; tl < 16; ++tl) acc[tl] = MFMA16(aP, wihR[tl], zero4);
#pragma unroll
            for (int tl = 0; tl < 16; ++tl) {
                const short* rbp = &sWhh[(tl * 16 + n) * 72 + q * 8];
                f4 t0 = acc[tl];
                t0 = MFMA16(ah0, *(const short8*)rbp, t0);
                t0 = MFMA16(ah1, *(const short8*)(rbp + 32), t0);
                acc[tl] = t0;
            }
            CFENCE();
#pragma unroll
            for (int u = 0; u < 4; ++u)
#pragma unroll
                for (int r = 0; r < 4; ++r) {
                    float ip = acc[u][r] + bias16[u];
                    float fp = acc[4 + u][r] + bias16[4 + u];
                    float gp = acc[8 + u][r] + bias16[8 + u];
                    float op = acc[12 + u][r] + bias16[12 + u];
                    float cc = fmaf(sigm_(fp), cst[r][u], sigm_(ip) * tanh2_(gp));
                    cst[r][u] = cc;
                    float hh = sigm_(op) * tanh2_(cc);
                    if (doRelu) hh = fmaxf(hh, 0.f);
                    hA[(q * 4 + r) * 72 + u * 16 + n] = f2bf(hh);
                }
            CFENCE();
        };
        // comb = relu([root,last]@Wc^T+bc) for 16 units; D unit m=q*4+r
        auto combMM = [&](short8 aroot, short* dst, int strideSel) {
            short8 lh0 = *(const short8*)&hA[n * 72 + q * 8];
            short8 lh1 = *(const short8*)&hA[n * 72 + 32 + q * 8];
#pragma unroll
            for (int tl2 = 0; tl2 < 2; ++tl2) {
                float bv = bc2[tl2];
                f4 t0 = {bv, bv, bv, bv};
                short8 b1 = *(const short8*)&wc1[(tl2 * 16 + n) * 32 + q * 8];
                t0 = MFMA16(aroot, b1, t0);
                const short* rbp = &wc2[(tl2 * 16 + n) * 64 + q * 8];
                t0 = MFMA16(lh0, *(const short8*)rbp, t0);
                t0 = MFMA16(lh1, *(const short8*)(rbp + 32), t0);
#pragma unroll
                for (int r = 0; r < 4; ++r) {
                    int ui = strideSel ? (q * 4 + r) : r;  // phase2: quads duplicate rows
                    dst[ui * 40 + tl2 * 16 + n] = f2bf(fmaxf(t0[r], 0.f));
                }
            }
            CFENCE();
        };

#pragma unroll 1
        for (int it = gw; it * 4 < nH; it += NW) {
            const int base = it * 4;
            // row of this lane's quad (uniform within quad)
            int idxq = min(base + q, nH - 1);
            int sl = 0;
#pragma unroll
            for (int b2 = 0; b2 < 32; ++b2) sl += (__shfl(vIncl, b2) <= idxq) ? 1 : 0;
            const int row = listH[sl * 1024 + idxq - __shfl(vExcl, sl)];
            const int tokAll = x[row * 16 + n];  // lane (q,n) holds x[row_q][n]
            const int liBase = (n & 3) * 16 + (n >> 2) * 4;  // unit n: row n&3, node n>>2

            // ---- phase 1: 4 rows x 4 nodes in the 16 units, 4 steps ----
            initSt();
            int tok = __shfl(tokAll, liBase);
            short8 aNext = *(const short8*)&embH[tok * 32 + q * 8];
            const short8 aRoot = aNext;
#pragma unroll 1
            for (int t = 0; t < 4; ++t) {
                short8 aP = aNext;
                if (t < 3) {
                    int tk2 = __shfl(tokAll, liBase + t + 1);
                    aNext = *(const short8*)&embH[tk2 * 32 + q * 8];
                }
                doStep(aP, t == 3);  // step 3 writes relu(h) = "last"
            }
            combMM(aRoot, cmb, 1);   // cmb[(node*4+row)][40]

            // ---- phase 2: node 4 (children = comb_0..3), rows duplicated x4 ----
            initSt();
            int tokR = __shfl(tokAll, (n & 3) * 16);
            short8 aR4 = *(const short8*)&embH[tokR * 32 + q * 8];
#pragma unroll 1
            for (int t = 0; t < 4; ++t) {
                short8 aC = *(const short8*)&cmb[(t * 4 + (n & 3)) * 40 + q * 8];
                doStep(aC, t == 3);
            }
            combMM(aR4, c4, 0);      // c4[row][40] (4 quads write identical)

            // ---- phase 3: logits + log_softmax for 4 rows ----
            short8 cA = *(const short8*)&c4[(n & 3) * 40 + q * 8];
            f4 a3[4];
#pragma unroll
            for (int tl3 = 0; tl3 < 4; ++tl3) {
                float bv = bt4[tl3];
                f4 t0 = {bv, bv, bv, bv};
                short8 bW = *(const short8*)&wth[(tl3 * 16 + n) * 32 + q * 8];
                a3[tl3] = MFMA16(cA, bW, t0);
            }
#pragma unroll
            for (int r = 0; r < 4; ++r) {
                float l0 = a3[0][r], l1 = a3[1][r], l2 = a3[2][r], l3 = a3[3][r];
                float mx = fmaxf(fmaxf(l0, l1), fmaxf(l2, l3));
#pragma unroll
                for (int o2 = 8; o2; o2 >>= 1) mx = fmaxf(mx, __shfl_xor(mx, o2));
                float sm = __expf(l0 - mx) + __expf(l1 - mx) +
                           __expf(l2 - mx) + __expf(l3 - mx);
#pragma unroll
                for (int o2 = 8; o2; o2 >>= 1) sm += __shfl_xor(sm, o2);
                float lse = mx + __logf(sm);
                if (q == r && base + r < nH) {  // quad r owns row r
                    out[row * 64 + n] = l0 - lse;
                    out[row * 64 + 16 + n] = l1 - lse;
                    out[row * 64 + 32 + n] = l2 - lse;
                    out[row * 64 + 48 + n] = l3 - lse;
                }
            }
        }
    }

    // ---- light rows: out depends only on x[row][0] ----
    if (nL > 0) {
        const int jm = lane & 31;
        float wcr[32], wtr[32];
#pragma unroll
        for (int k4 = 0; k4 < 8; ++k4) {
            f4 wv2 = *(const f4*)&Wc[jm * 96 + k4 * 4];
            wcr[4 * k4] = wv2[0]; wcr[4 * k4 + 1] = wv2[1];
            wcr[4 * k4 + 2] = wv2[2]; wcr[4 * k4 + 3] = wv2[3];
            f4 tv = *(const f4*)&Wt[lane * 32 + k4 * 4];
            wtr[4 * k4] = tv[0]; wtr[4 * k4 + 1] = tv[1];
            wtr[4 * k4 + 2] = tv[2]; wtr[4 * k4 + 3] = tv[3];
        }
        const float bcj = bc[jm], btj = bt[lane];
        auto lookupL = [&](int i) {
            unsigned long long m = __ballot((lane < 32) && (liIncl <= i));
            int slab = __popcll(m);
            return listL[slab * 1024 + i - __shfl(liExcl, slab)];
        };
        int i = gw;
        int row = 0, tok = 0;
        if (i < nL) { row = lookupL(i); tok = x[row * 16]; }
#pragma unroll 1
        while (i < nL) {
            int inext = i + NW;
            int rowN = 0, tokN = 0;
            if (inext < nL) { rowN = lookupL(inext); tokN = x[rowN * 16]; }  // in flight
            const f4* ep = (const f4*)&emb[tok * 32];
            float a = bcj;
#pragma unroll
            for (int k4 = 0; k4 < 8; ++k4) {
                f4 ev = ep[k4];
                a = fmaf(ev[0], wcr[4 * k4], a);
                a = fmaf(ev[1], wcr[4 * k4 + 1], a);
                a = fmaf(ev[2], wcr[4 * k4 + 2], a);
                a = fmaf(ev[3], wcr[4 * k4 + 3], a);
            }
            float comb = fmaxf(a, 0.f);
            float logit = btj;
#pragma unroll
            for (int k = 0; k < 32; ++k) logit = fmaf(__shfl(comb, k), wtr[k], logit);
            float mx = logit;
#pragma unroll
            for (int o2 = 32; o2; o2 >>= 1) mx = fmaxf(mx, __shfl_xor(mx, o2));
            float ex = __expf(logit - mx), sm = ex;
#pragma unroll
            for (int o2 = 32; o2; o2 >>= 1) sm += __shfl_xor(sm, o2);
            out[row * 64 + lane] = logit - mx - __logf(sm);
            row = rowN; tok = tokN; i = inext;
        }
    }
}

// ---------------- fallback (small ws): monolithic fp32 kernel ----------------
__global__ __launch_bounds__(512) void tagger_fallback(
    const int* __restrict__ x, const int* __restrict__ s, const float* __restrict__ emb,
    const float* __restrict__ Wih, const float* __restrict__ Whh,
    const float* __restrict__ bih, const float* __restrict__ bhh,
    const float* __restrict__ h0, const float* __restrict__ c0,
    const float* __restrict__ Wc, const float* __restrict__ bc,
    const float* __restrict__ Wt, const float* __restrict__ bt,
    float* __restrict__ out) {
    __shared__ float4 WhhP[4096];
    __shared__ float combBuf[8][128];
    for (int i = threadIdx.x; i < 4096; i += 512) {
        int k = i & 63, jj = i >> 6;
        WhhP[k * 64 + jj] = make_float4(Whh[jj * 64 + k], Whh[(jj + 64) * 64 + k],
                                        Whh[(jj + 128) * 64 + k], Whh[(jj + 192) * 64 + k]);
    }
    __syncthreads();
    const int wave = threadIdx.x >> 6, j = threadIdx.x & 63, jm = j & 31;
    const int b = blockIdx.x * 8 + wave;
    const int sv = s[b];
    const int* xb = x + b * NT;
    const float bcj = bc[jm];
    auto rc_val = [&](int tok) -> float {
        float r = 0.f;
#pragma unroll
        for (int k = 0; k < 32; ++k) r = fmaf(emb[tok * NE + k], Wc[jm * 96 + k], r);
        return r;
    };
    float comb4;
    if (sv >= 4) {
        const float h0j = h0[j], c0j = c0[j];
        float4 bsj = make_float4(bih[j] + bhh[j], bih[j + 64] + bhh[j + 64],
                                 bih[j + 128] + bhh[j + 128], bih[j + 192] + bhh[j + 192]);
#pragma unroll 1
        for (int node = 0; node < 4; ++node) {
            float h = h0j, c = c0j;
#pragma unroll 1
            for (int t = 0; t < 4; ++t) {
                int tok = xb[node * 4 + t];
                float4 p = bsj;
#pragma unroll
                for (int k = 0; k < 32; ++k) {
                    float e = emb[tok * NE + k];
                    p.x = fmaf(e, Wih[j * 32 + k], p.x);
                    p.y = fmaf(e, Wih[(j + 64) * 32 + k], p.y);
                    p.z = fmaf(e, Wih[(j + 128) * 32 + k], p.z);
                    p.w = fmaf(e, Wih[(j + 192) * 32 + k], p.w);
                }
                float4 a = make_float4(0.f, 0.f, 0.f, 0.f);
#pragma unroll
                for (int k = 0; k < 64; ++k) {
                    float hk = __shfl(h, k);
                    float4 w = WhhP[k * 64 + j];
                    a.x = fmaf(hk, w.x, a.x); a.y = fmaf(hk, w.y, a.y);
                    a.z = fmaf(hk, w.z, a.z); a.w = fmaf(hk, w.w, a.w);
                }
                a.x += p.x; a.y += p.y; a.z += p.z; a.w += p.w;
                float ig = sigm_(a.x), fg = sigm_(a.y), gg = tanh2_(a.z), og = sigm_(a.w);
                c = fmaf(fg, c, ig * gg);
                h = og * tanh2_(c);
            }
            float last = fmaxf(h, 0.f);
            float acc = rc_val(xb[node * 4]) + bcj;
#pragma unroll
            for (int k = 0; k < 64; ++k)
                acc = fmaf(__shfl(last, k), Wc[jm * 96 + 32 + k], acc);
            if (j < 32) combBuf[wave][node * 32 + j] = fmaxf(acc, 0.f);
        }
        LDSSYNC();
        float h = h0j, c = c0j;
#pragma unroll 1
        for (int t = 0; t < 4; ++t) {
            float4 a = make_float4(0.f, 0.f, 0.f, 0.f);
#pragma unroll
            for (int k = 0; k < 32; ++k) {
                float ck = combBuf[wave][t * 32 + k];
                a.x = fmaf(ck, Wih[j * 32 + k], a.x);
                a.y = fmaf(ck, Wih[(j + 64) * 32 + k], a.y);
                a.z = fmaf(ck, Wih[(j + 128) * 32 + k], a.z);
                a.w = fmaf(ck, Wih[(j + 192) * 32 + k], a.w);
            }
#pragma unroll
            for (int k = 0; k < 64; ++k) {
                float hk = __shfl(h, k);
                float4 w = WhhP[k * 64 + j];
                a.x = fmaf(hk, w.x, a.x); a.y = fmaf(hk, w.y, a.y);
                a.z = fmaf(hk, w.z, a.z); a.w = fmaf(hk, w.w, a.w);
            }
            a.x += bih[j] + bhh[j]; a.y += bih[j + 64] + bhh[j + 64];
            a.z += bih[j + 128] + bhh[j + 128]; a.w += bih[j + 192] + bhh[j + 192];
            float ig = sigm_(a.x), fg = sigm_(a.y), gg = tanh2_(a.z), og = sigm_(a.w);
            c = fmaf(fg, c, ig * gg);
            h = og * tanh2_(c);
        }
        float last = fmaxf(h, 0.f);
        float acc = rc_val(xb[0]) + bcj;
#pragma unroll
        for (int k = 0; k < 64; ++k)
            acc = fmaf(__shfl(last, k), Wc[jm * 96 + 32 + k], acc);
        comb4 = fmaxf(acc, 0.f);
    } else {
        comb4 = fmaxf(rc_val(xb[0]) + bcj, 0.f);
    }
    float logit = bt[j];
    const float* wtr = Wt + j * 32;
#pragma unroll
    for (int k = 0; k < 32; ++k) logit = fmaf(__shfl(comb4, k), wtr[k], logit);
    float mx = logit;
#pragma unroll
    for (int off = 32; off; off >>= 1) mx = fmaxf(mx, __shfl_xor(mx, off));
    float ex = __expf(logit - mx);
    float sum = ex;
#pragma unroll
    for (int off = 32; off; off >>= 1) sum += __shfl_xor(sum, off);
    out[b * 64 + j] = logit - mx - __logf(sum);
}

extern "C" void kernel_launch(void* const* d_in, const int* in_sizes, int n_in,
                              void* d_out, int out_size, void* d_ws, size_t ws_size,
                              hipStream_t stream) {
    const int* x = (const int*)d_in[0];
    const int* s = (const int*)d_in[1];
    const float* emb = (const float*)d_in[2];
    const float* Wih = (const float*)d_in[3];
    const float* Whh = (const float*)d_in[4];
    const float* bih = (const float*)d_in[5];
    const float* bhh = (const float*)d_in[6];
    const float* h0 = (const float*)d_in[7];
    const float* c0 = (const float*)d_in[8];
    const float* Wc = (const float*)d_in[9];
    const float* bc = (const float*)d_in[10];
    const float* Wt = (const float*)d_in[11];
    const float* bt = (const float*)d_in[12];
    float* out = (float*)d_out;

    auto al16 = [](size_t v) { return (v + 15) & ~(size_t)15; };
    size_t off = 0;
    size_t oWpack = off; off = al16(off + (size_t)28672 * 2);  // WhhHi[256x72]+WihHi[256x40]
    size_t oWc1 = off;   off = al16(off + 1024 * 2);
    size_t oWc2 = off;   off = al16(off + 2048 * 2);
    size_t oWt = off;    off = al16(off + 2048 * 2);
    size_t oBsum = off;  off = al16(off + 256 * 4);
    size_t oEmbH = off;  off = al16(off + (size_t)NV * NE * 2);
    size_t oCH = off;    off = al16(off + 32 * 4);
    size_t oListH = off; off = al16(off + (size_t)NB * 4);
    size_t oListL = off; off = al16(off + (size_t)NB * 4);
    size_t need = off;

    char* ws = (char*)d_ws;
    if (ws_size >= need) {
        short* wpack = (short*)(ws + oWpack);
        short* wc1 = (short*)(ws + oWc1);
        short* wc2 = (short*)(ws + oWc2);
        short* wth = (short*)(ws + oWt);
        float* bsum = (float*)(ws + oBsum);
        short* embH = (short*)(ws + oEmbH);
        int* cHp = (int*)(ws + oCH);
        int* listH = (int*)(ws + oListH);
        int* listL = (int*)(ws + oListL);

        classify_prep<<<dim3(256), dim3(1024), 0, stream>>>(
            s, emb, Wih, Whh, bih, bhh, Wc, Wt,
            embH, wpack, wc1, wc2, wth, bsum, cHp, listH, listL);
        main_fused<<<dim3(512), dim3(256), 0, stream>>>(
            x, emb, h0, c0, Wc, bc, Wt, bt, bsum,
            wpack, wc1, wc2, wth, embH, cHp, listH, listL, out);
    } else {
        tagger_fallback<<<dim3(4096), dim3(512), 0, stream>>>(
            x, s, emb, Wih, Whh, bih, bhh, h0, c0, Wc, bc, Wt, bt, out);
    }
}